// Round 8
// baseline (6280.175 us; speedup 1.0000x reference)
//
#include <hip/hip_runtime.h>
#include <hip/hip_bf16.h>
#include <math.h>

// All dimensions derived AT RUNTIME from in_sizes/out_size.
// Inputs: float32. OUTPUTS: float32 (reference returns jnp.float32; harness
// compares f32 buffer against bf16-rounded ref with bf16-floored threshold).
// Reference shapes: x(B,T,H), W_tt(C1,H), b_tt(C1), W_pol(C2,H), b_pol(C2),
// W_c2h(H,DIN), b_c2h(H), W_ih(3H,DIN), W_hh(3H,H), b_ih(3H), b_hh(3H),
// W_proj(V,H), b_proj(V), W1(V,H,DIN), b1(V,H), W2(V,H,H), b2(V,H)
// Outputs (flat, return order): out(B,T,H), logits(B,L,V), tt(B,T,C1),
// pol(B,T,C2), pooled(B,H).

__device__ __forceinline__ float wsum(float v) {
#pragma unroll
  for (int off = 32; off; off >>= 1) v += __shfl_xor(v, off, 64);
  return v;
}

// ---------- concept feats: one wave per site ----------
__global__ void k_feats(const float* __restrict__ x,
                        const float* __restrict__ Wtt, const float* __restrict__ btt,
                        const float* __restrict__ Wpol, const float* __restrict__ bpol,
                        float* __restrict__ out_tt, float* __restrict__ out_pol,
                        float* __restrict__ feats, float* __restrict__ fsum,
                        int H, int T, int BT, int C1, int C2) {
  int wave = threadIdx.x >> 6, lane = threadIdx.x & 63;
  int site = blockIdx.x * 4 + wave;
  if (site >= BT) return;
  int DC = C1 + C2;
  int b = site / T;
  const float* xp = x + (size_t)site * H;
  float acc[16];
  for (int c = 0; c < DC; c++) acc[c] = 0.f;
  for (int k = lane; k < H; k += 64) {
    float xv = xp[k];
    for (int c = 0; c < C1; c++) acc[c] += xv * Wtt[(size_t)c * H + k];
    for (int c = 0; c < C2; c++) acc[C1 + c] += xv * Wpol[(size_t)c * H + k];
  }
  for (int c = 0; c < DC; c++) acc[c] = wsum(acc[c]);
  if (lane == 0) {
    for (int c = 0; c < DC; c++) {
      float val = acc[c] + (c < C1 ? btt[c] : bpol[c - C1]);
      if (c < C1) out_tt[(size_t)site * C1 + c] = val;
      else        out_pol[(size_t)site * C2 + (c - C1)] = val;
      feats[(size_t)site * DC + c] = val;
      atomicAdd(&fsum[b * DC + c], val / (float)T);
    }
  }
}

// ---------- pooled mean over T (direct write, no atomics) ----------
__global__ void k_pool(const float* __restrict__ x, float* __restrict__ pooled,
                       int H, int T) {
  int hBlocks = (H + 255) / 256;
  int b = blockIdx.x / hBlocks;
  int h = (blockIdx.x % hBlocks) * 256 + threadIdx.x;
  if (h >= H) return;
  const float* p = x + (size_t)b * T * H + h;
  float s = 0.f;
  for (int t = 0; t < T; t++) s += p[(size_t)t * H];
  pooled[(size_t)b * H + h] = s / (float)T;
}

// ---------- context -> h0; emit pooled output ----------
__global__ void k_ctx_h0(const float* __restrict__ Wc2h, const float* __restrict__ bc2h,
                         const float* __restrict__ pooled, const float* __restrict__ fmean,
                         float* __restrict__ h0, float* __restrict__ out_pool,
                         int H, int DIN, int B, int DC) {
  int wave = threadIdx.x >> 6, lane = threadIdx.x & 63;
  int r = blockIdx.x * 4 + wave;
  if (r >= B * H) return;
  int b = r / H, j = r % H;
  const float* wrow = Wc2h + (size_t)j * DIN;
  float a = 0.f;
  for (int k = lane; k < DIN; k += 64) {
    float cv = (k < H) ? pooled[(size_t)b * H + k] : fmean[b * DC + (k - H)];
    a += cv * wrow[k];
  }
  a = wsum(a);
  if (lane == 0) {
    h0[r] = a + bc2h[j];
    out_pool[r] = pooled[r];
  }
}

// ---------- one GRU step (zero input => gi = b_ih) ----------
__global__ void k_gru(const float* __restrict__ hin, const float* __restrict__ Whh,
                      const float* __restrict__ bih, const float* __restrict__ bhh,
                      float* __restrict__ hout, float* __restrict__ hsl,
                      int H, int B) {
  int wave = threadIdx.x >> 6, lane = threadIdx.x & 63;
  int r = blockIdx.x * 4 + wave;
  if (r >= B * H) return;
  int b = r / H, j = r % H;
  const float* h = hin + (size_t)b * H;
  const float* w0 = Whh + (size_t)j * H;
  const float* w1 = Whh + (size_t)(H + j) * H;
  const float* w2 = Whh + (size_t)(2 * H + j) * H;
  float ar = 0, az = 0, an = 0;
  for (int k = lane; k < H; k += 64) {
    float hv = h[k];
    ar += hv * w0[k];
    az += hv * w1[k];
    an += hv * w2[k];
  }
  ar = wsum(ar); az = wsum(az); an = wsum(an);
  if (lane == 0) {
    float ghr = ar + bhh[j];
    float ghz = az + bhh[H + j];
    float ghn = an + bhh[2 * H + j];
    float rg = 1.f / (1.f + expf(-(bih[j] + ghr)));
    float zg = 1.f / (1.f + expf(-(bih[H + j] + ghz)));
    float ng = tanhf(bih[2 * H + j] + rg * ghn);
    float hn = (1.f - zg) * ng + zg * h[j];
    hout[r] = hn;
    hsl[r] = hn;
  }
}

// ---------- program logits ----------
__global__ void k_logits(const float* __restrict__ hs, const float* __restrict__ Wproj,
                         const float* __restrict__ bproj, float* __restrict__ logits,
                         float* __restrict__ out_log, int H, int B, int L, int V) {
  int wave = threadIdx.x >> 6, lane = threadIdx.x & 63;
  int r = blockIdx.x * 4 + wave;
  if (r >= B * L * V) return;
  int b = r / (L * V), rem = r % (L * V), l = rem / V, u = rem % V;
  const float* h = hs + ((size_t)l * B + b) * H;
  const float* w = Wproj + (size_t)u * H;
  float a = 0.f;
  for (int k = lane; k < H; k += 64) a += h[k] * w[k];
  a = wsum(a);
  if (lane == 0) {
    a += bproj[u];
    int idx = (b * L + l) * V + u;
    logits[idx] = a;
    out_log[idx] = a;
  }
}

// ---------- w[b,v] = mean_l softmax(logits)  and  wb2[b,o] = sum_v w*b2 ----------
__global__ void k_wmix(const float* __restrict__ logits, const float* __restrict__ b2,
                       float* __restrict__ wv, float* __restrict__ wb2,
                       int B, int L, int V, int H) {
  __shared__ float sm[2048];
  __shared__ float wsh[512];
  int t = threadIdx.x;
  if (t < B * L) {
    const float* lg = logits + t * V;
    float mx = lg[0];
    for (int u = 1; u < V; u++) mx = fmaxf(mx, lg[u]);
    float s = 0.f;
    for (int u = 0; u < V; u++) s += expf(lg[u] - mx);
    for (int u = 0; u < V; u++) sm[t * V + u] = expf(lg[u] - mx) / s;
  }
  __syncthreads();
  if (t < B * V) {
    int b = t / V, u = t % V;
    float a = 0.f;
    for (int l = 0; l < L; l++) a += sm[(b * L + l) * V + u];
    a /= (float)L;
    wsh[t] = a;
    wv[t] = a;
  }
  __syncthreads();
  for (int idx = t; idx < B * H; idx += 256) {
    int b = idx / H, o = idx % H;
    float a = 0.f;
    for (int u = 0; u < V; u++) a += wsh[b * V + u] * b2[(size_t)u * H + o];
    wb2[idx] = a;
  }
}

// ---------- GEMM1 per v: hmid[m,n] = gelu( x[m,:]·W1v[n,:H] + b1v[n] + feats[m,:]·W1v[n,H:] ) ----------
__global__ __launch_bounds__(256) void k_gemm1(
    const float* __restrict__ A,    // x + moff*H
    const float* __restrict__ Bm,   // W1v, row stride DIN
    float* __restrict__ Cm,         // hmid chunk (f32), row stride H
    int rows, int moff, int H, int DIN,
    const float* __restrict__ feats, int DC, const float* __restrict__ b1v) {
  __shared__ float As[64][17];
  __shared__ float Bs[64][17];
  int t = threadIdx.x;
  int tx = t & 15, ty = t >> 4;
  int m0 = blockIdx.y * 64, n0 = blockIdx.x * 64;
  int lRow = t >> 2, lK = (t & 3) * 4;
  float acc[4][4];
#pragma unroll
  for (int i = 0; i < 4; i++)
#pragma unroll
    for (int j = 0; j < 4; j++) acc[i][j] = 0.f;
  int aRow = m0 + lRow; if (aRow >= rows) aRow = rows - 1;
  int bRow = n0 + lRow; if (bRow >= H) bRow = H - 1;
  const float* Ap = A + (size_t)aRow * H + lK;
  const float* Bp = Bm + (size_t)bRow * DIN + lK;
  for (int k0 = 0; k0 < H; k0 += 16) {
    float4 av = *(const float4*)(Ap + k0);
    float4 bv = *(const float4*)(Bp + k0);
    __syncthreads();
    As[lRow][lK + 0] = av.x; As[lRow][lK + 1] = av.y;
    As[lRow][lK + 2] = av.z; As[lRow][lK + 3] = av.w;
    Bs[lRow][lK + 0] = bv.x; Bs[lRow][lK + 1] = bv.y;
    Bs[lRow][lK + 2] = bv.z; Bs[lRow][lK + 3] = bv.w;
    __syncthreads();
#pragma unroll
    for (int kk = 0; kk < 16; ++kk) {
      float a_[4], b_[4];
#pragma unroll
      for (int i = 0; i < 4; i++) a_[i] = As[ty + 16 * i][kk];
#pragma unroll
      for (int j = 0; j < 4; j++) b_[j] = Bs[tx + 16 * j][kk];
#pragma unroll
      for (int i = 0; i < 4; i++)
#pragma unroll
        for (int j = 0; j < 4; j++) acc[i][j] += a_[i] * b_[j];
    }
  }
#pragma unroll
  for (int i = 0; i < 4; i++) {
    int m = m0 + ty + 16 * i;
    if (m >= rows) continue;
    float fm[16];
    for (int d = 0; d < DC; d++) fm[d] = feats[(size_t)(moff + m) * DC + d];
#pragma unroll
    for (int j = 0; j < 4; j++) {
      int n = n0 + tx + 16 * j;
      if (n >= H) continue;
      float val = acc[i][j] + b1v[n];
      const float* tail = Bm + (size_t)n * DIN + H;
      for (int d = 0; d < DC; d++) val += fm[d] * tail[d];
      val = 0.5f * val * (1.0f + erff(val * 0.70710678118654752f));
      Cm[(size_t)m * H + n] = val;
    }
  }
}

// ---------- GEMM2 per v: out[gm,n] += w[b,v] * (hmid[m,:]·W2v[n,:]) (+ wb2 on first v) ----------
__global__ __launch_bounds__(256) void k_gemm2(
    const float* __restrict__ A,    // hmid chunk (f32), row stride H
    const float* __restrict__ Bm,   // W2v, row stride H
    float* __restrict__ Cm,         // out_y (f32, global rows)
    int rows, int moff, int H, int T,
    const float* __restrict__ wv, int V, int v, int first,
    const float* __restrict__ wb2) {
  __shared__ float As[64][17];
  __shared__ float Bs[64][17];
  int t = threadIdx.x;
  int tx = t & 15, ty = t >> 4;
  int m0 = blockIdx.y * 64, n0 = blockIdx.x * 64;
  int lRow = t >> 2, lK = (t & 3) * 4;
  float acc[4][4];
#pragma unroll
  for (int i = 0; i < 4; i++)
#pragma unroll
    for (int j = 0; j < 4; j++) acc[i][j] = 0.f;
  int aRow = m0 + lRow; if (aRow >= rows) aRow = rows - 1;
  int bRow = n0 + lRow; if (bRow >= H) bRow = H - 1;
  const float* Ap = A + (size_t)aRow * H + lK;
  const float* Bp = Bm + (size_t)bRow * H + lK;
  for (int k0 = 0; k0 < H; k0 += 16) {
    float4 av = *(const float4*)(Ap + k0);
    float4 bv = *(const float4*)(Bp + k0);
    __syncthreads();
    As[lRow][lK + 0] = av.x; As[lRow][lK + 1] = av.y;
    As[lRow][lK + 2] = av.z; As[lRow][lK + 3] = av.w;
    Bs[lRow][lK + 0] = bv.x; Bs[lRow][lK + 1] = bv.y;
    Bs[lRow][lK + 2] = bv.z; Bs[lRow][lK + 3] = bv.w;
    __syncthreads();
#pragma unroll
    for (int kk = 0; kk < 16; ++kk) {
      float a_[4], b_[4];
#pragma unroll
      for (int i = 0; i < 4; i++) a_[i] = As[ty + 16 * i][kk];
#pragma unroll
      for (int j = 0; j < 4; j++) b_[j] = Bs[tx + 16 * j][kk];
#pragma unroll
      for (int i = 0; i < 4; i++)
#pragma unroll
        for (int j = 0; j < 4; j++) acc[i][j] += a_[i] * b_[j];
    }
  }
#pragma unroll
  for (int i = 0; i < 4; i++) {
    int m = m0 + ty + 16 * i;
    if (m >= rows) continue;
    int gm = moff + m;
    int b = gm / T;
    float wvb = wv[b * V + v];
#pragma unroll
    for (int j = 0; j < 4; j++) {
      int n = n0 + tx + 16 * j;
      if (n >= H) continue;
      float val = wvb * acc[i][j];
      if (first) val += wb2[(size_t)b * H + n];
      else       val += Cm[(size_t)gm * H + n];
      Cm[(size_t)gm * H + n] = val;
    }
  }
}

extern "C" void kernel_launch(void* const* d_in, const int* in_sizes, int n_in,
                              void* d_out, int out_size, void* d_ws, size_t ws_size,
                              hipStream_t stream) {
  const float* x      = (const float*)d_in[0];
  const float* W_tt   = (const float*)d_in[1];
  const float* b_tt   = (const float*)d_in[2];
  const float* W_pol  = (const float*)d_in[3];
  const float* b_pol  = (const float*)d_in[4];
  const float* W_c2h  = (const float*)d_in[5];
  const float* b_c2h  = (const float*)d_in[6];
  const float* W_hh   = (const float*)d_in[8];
  const float* b_ih   = (const float*)d_in[9];
  const float* b_hh   = (const float*)d_in[10];
  const float* W_proj = (const float*)d_in[11];
  const float* b_proj = (const float*)d_in[12];
  const float* W1     = (const float*)d_in[13];
  const float* b1     = (const float*)d_in[14];
  const float* W2     = (const float*)d_in[15];
  const float* b2     = (const float*)d_in[16];
  float* out = (float*)d_out;
  char* ws = (char*)d_ws;

  // ---- derive dimensions from in_sizes / out_size ----
  const int C1 = in_sizes[2];                 // b_tt
  const int C2 = in_sizes[4];                 // b_pol
  const int H  = in_sizes[1] / C1;            // W_tt = (C1,H)
  const int DC = C1 + C2;
  const int DIN = H + DC;
  const int V  = in_sizes[12];                // b_proj
  const long BT = (long)in_sizes[0] / H;      // x = (B*T, H)
  long R = (long)out_size - BT * (long)(H + DC);
  int B = 0, L = 0;
  for (int Lc = 1; Lc <= 32; ++Lc) {          // out_size = BT*(H+DC) + B*(L*V+H)
    long den = (long)Lc * V + H;
    if (R % den == 0) {
      long Bc = R / den;
      if (Bc >= 1 && BT % Bc == 0) {
        if (B == 0 || Lc == 4) { B = (int)Bc; L = Lc; }
        if (Lc == 4) break;
      }
    }
  }
  if (B == 0) { B = 8; L = 4; }               // fallback (reference dims)
  const int T = (int)(BT / B);

  // ---- workspace layout (runtime; keep total small) ----
  size_t o = 0;
  auto alloc = [&](size_t bytes) { size_t r = o; o = (o + bytes + 255) & ~(size_t)255; return r; };
  long McL = (1L * 1024 * 1024) / H; if (McL > BT) McL = BT;
  int Mc = (int)(McL / 64) * 64; if (Mc < 64) Mc = 64;
  float* hmid   = (float*)(ws + alloc((size_t)Mc * H * 4));
  float* feats  = (float*)(ws + alloc((size_t)BT * DC * 4));
  float* pooled = (float*)(ws + alloc((size_t)B * H * 4));
  float* fsum   = (float*)(ws + alloc((size_t)B * DC * 4));
  float* hbuf   = (float*)(ws + alloc((size_t)2 * B * H * 4));
  float* hs     = (float*)(ws + alloc((size_t)L * B * H * 4));
  float* logits = (float*)(ws + alloc((size_t)B * L * V * 4));
  float* wv     = (float*)(ws + alloc((size_t)B * V * 4));
  float* wb2    = (float*)(ws + alloc((size_t)B * H * 4));

  // ---- output layout (flat f32, return order) ----
  float* out_y    = out;
  float* out_log  = out_y + (size_t)BT * H;
  float* out_tt   = out_log + (size_t)B * L * V;
  float* out_pol  = out_tt + (size_t)BT * C1;
  float* out_pool = out_pol + (size_t)BT * C2;

  hipMemsetAsync(fsum, 0, (size_t)B * DC * 4, stream);

  k_feats<<<(int)((BT + 3) / 4), 256, 0, stream>>>(x, W_tt, b_tt, W_pol, b_pol,
                                                   out_tt, out_pol, feats, fsum,
                                                   H, T, (int)BT, C1, C2);
  k_pool<<<B * ((H + 255) / 256), 256, 0, stream>>>(x, pooled, H, T);
  k_ctx_h0<<<(B * H + 3) / 4, 256, 0, stream>>>(W_c2h, b_c2h, pooled, fsum,
                                                hbuf, out_pool, H, DIN, B, DC);
  float* hA = hbuf;
  float* hB = hbuf + (size_t)B * H;
  for (int l = 0; l < L; ++l) {
    k_gru<<<(B * H + 3) / 4, 256, 0, stream>>>((l & 1) ? hB : hA, W_hh, b_ih, b_hh,
                                               (l & 1) ? hA : hB, hs + (size_t)l * B * H,
                                               H, B);
  }
  k_logits<<<(B * L * V + 3) / 4, 256, 0, stream>>>(hs, W_proj, b_proj, logits,
                                                    out_log, H, B, L, V);
  k_wmix<<<1, 256, 0, stream>>>(logits, b2, wv, wb2, B, L, V, H);

  for (long moff = 0; moff < BT; moff += Mc) {
    int rows = (int)((BT - moff < Mc) ? (BT - moff) : Mc);
    dim3 g((H + 63) / 64, (rows + 63) / 64);
    for (int v = 0; v < V; ++v) {
      const float* W1v = W1 + (size_t)v * H * DIN;
      const float* b1v = b1 + (size_t)v * H;
      const float* W2v = W2 + (size_t)v * H * H;
      k_gemm1<<<g, 256, 0, stream>>>(x + (size_t)moff * H, W1v, hmid,
                                     rows, (int)moff, H, DIN, feats, DC, b1v);
      k_gemm2<<<g, 256, 0, stream>>>(hmid, W2v, out_y,
                                     rows, (int)moff, H, T, wv, V, v,
                                     (v == 0) ? 1 : 0, wb2);
    }
  }
}

// Round 9
// 1391.898 us; speedup vs baseline: 4.5120x; 4.5120x over previous
//
#include <hip/hip_runtime.h>
#include <hip/hip_bf16.h>
#include <math.h>

typedef __bf16 bf16;
typedef __bf16 bf16x8 __attribute__((ext_vector_type(8)));
typedef float f32x4 __attribute__((ext_vector_type(4)));

// Dims derived at runtime. Inputs f32, outputs f32.
// x(B,T,H), W_tt(C1,H), b_tt, W_pol(C2,H), b_pol, W_c2h(H,DIN), b_c2h,
// W_ih(3H,DIN), W_hh(3H,H), b_ih, b_hh, W_proj(V,H), b_proj,
// W1(V,H,DIN), b1(V,H), W2(V,H,H), b2(V,H).
// Outputs: out(B,T,H), logits(B,L,V), tt(B,T,C1), pol(B,T,C2), pooled(B,H).

__device__ __forceinline__ float wsum(float v) {
#pragma unroll
  for (int off = 32; off; off >>= 1) v += __shfl_xor(v, off, 64);
  return v;
}

__device__ __forceinline__ bf16x8 cvt8(const float* p) {
  float4 a = *(const float4*)p;
  float4 b = *(const float4*)(p + 4);
  bf16x8 r;
  r[0] = (bf16)a.x; r[1] = (bf16)a.y; r[2] = (bf16)a.z; r[3] = (bf16)a.w;
  r[4] = (bf16)b.x; r[5] = (bf16)b.y; r[6] = (bf16)b.z; r[7] = (bf16)b.w;
  return r;
}

// ---------- concept feats: one wave per site; reg-resident accumulators ----------
__global__ void k_feats(const float* __restrict__ x,
                        const float* __restrict__ Wtt, const float* __restrict__ btt,
                        const float* __restrict__ Wpol, const float* __restrict__ bpol,
                        float* __restrict__ out_tt, float* __restrict__ out_pol,
                        float* __restrict__ feats, float* __restrict__ fsum,
                        int H, int T, int BT, int C1, int C2) {
  int wave = threadIdx.x >> 6, lane = threadIdx.x & 63;
  int site = blockIdx.x * 4 + wave;
  if (site >= BT) return;
  int DC = C1 + C2;
  int b = site / T;
  const float* xp = x + (size_t)site * H;
  const float* wp[16];
#pragma unroll
  for (int c = 0; c < 16; c++) {
    int cc = (c < DC) ? c : 0;
    wp[c] = (cc < C1) ? (Wtt + (size_t)cc * H) : (Wpol + (size_t)(cc - C1) * H);
  }
  float acc[16];
#pragma unroll
  for (int c = 0; c < 16; c++) acc[c] = 0.f;
  for (int k = lane; k < H; k += 64) {
    float xv = xp[k];
#pragma unroll
    for (int c = 0; c < 16; c++)
      if (c < DC) acc[c] += xv * wp[c][k];
  }
#pragma unroll
  for (int c = 0; c < 16; c++)
    if (c < DC) acc[c] = wsum(acc[c]);
  if (lane == 0) {
    for (int c = 0; c < DC; c++) {
      float val = acc[c] + (c < C1 ? btt[c] : bpol[c - C1]);
      if (c < C1) out_tt[(size_t)site * C1 + c] = val;
      else        out_pol[(size_t)site * C2 + (c - C1)] = val;
      feats[(size_t)site * DC + c] = val;
      atomicAdd(&fsum[b * DC + c], val / (float)T);
    }
  }
}

// ---------- pooled mean over T (8-way T-split, atomic accumulate) ----------
__global__ void k_pool(const float* __restrict__ x, float* __restrict__ pooled,
                       int H, int T, int tsplit) {
  int hBlocks = (H + 255) / 256;
  int bs = blockIdx.x / tsplit, ts = blockIdx.x % tsplit;
  int b = bs / hBlocks;
  int h = (bs % hBlocks) * 256 + threadIdx.x;
  if (h >= H) return;
  int tlo = (int)(((long)T * ts) / tsplit), thi = (int)(((long)T * (ts + 1)) / tsplit);
  const float* p = x + (size_t)b * T * H + h;
  float s = 0.f;
  for (int t = tlo; t < thi; t++) s += p[(size_t)t * H];
  atomicAdd(&pooled[(size_t)b * H + h], s / (float)T);
}

// ---------- context -> h0; emit pooled output ----------
__global__ void k_ctx_h0(const float* __restrict__ Wc2h, const float* __restrict__ bc2h,
                         const float* __restrict__ pooled, const float* __restrict__ fmean,
                         float* __restrict__ h0, float* __restrict__ out_pool,
                         int H, int DIN, int B, int DC) {
  int wave = threadIdx.x >> 6, lane = threadIdx.x & 63;
  int r = blockIdx.x * 4 + wave;
  if (r >= B * H) return;
  int b = r / H, j = r % H;
  const float* wrow = Wc2h + (size_t)j * DIN;
  float a = 0.f;
  for (int k = lane; k < DIN; k += 64) {
    float cv = (k < H) ? pooled[(size_t)b * H + k] : fmean[b * DC + (k - H)];
    a += cv * wrow[k];
  }
  a = wsum(a);
  if (lane == 0) {
    h0[r] = a + bc2h[j];
    out_pool[r] = pooled[r];
  }
}

// ---------- one GRU step ----------
__global__ void k_gru(const float* __restrict__ hin, const float* __restrict__ Whh,
                      const float* __restrict__ bih, const float* __restrict__ bhh,
                      float* __restrict__ hout, float* __restrict__ hsl,
                      int H, int B) {
  int wave = threadIdx.x >> 6, lane = threadIdx.x & 63;
  int r = blockIdx.x * 4 + wave;
  if (r >= B * H) return;
  int b = r / H, j = r % H;
  const float* h = hin + (size_t)b * H;
  const float* w0 = Whh + (size_t)j * H;
  const float* w1 = Whh + (size_t)(H + j) * H;
  const float* w2 = Whh + (size_t)(2 * H + j) * H;
  float ar = 0, az = 0, an = 0;
  for (int k = lane; k < H; k += 64) {
    float hv = h[k];
    ar += hv * w0[k];
    az += hv * w1[k];
    an += hv * w2[k];
  }
  ar = wsum(ar); az = wsum(az); an = wsum(an);
  if (lane == 0) {
    float ghr = ar + bhh[j];
    float ghz = az + bhh[H + j];
    float ghn = an + bhh[2 * H + j];
    float rg = 1.f / (1.f + expf(-(bih[j] + ghr)));
    float zg = 1.f / (1.f + expf(-(bih[H + j] + ghz)));
    float ng = tanhf(bih[2 * H + j] + rg * ghn);
    float hn = (1.f - zg) * ng + zg * h[j];
    hout[r] = hn;
    hsl[r] = hn;
  }
}

// ---------- program logits ----------
__global__ void k_logits(const float* __restrict__ hs, const float* __restrict__ Wproj,
                         const float* __restrict__ bproj, float* __restrict__ logits,
                         float* __restrict__ out_log, int H, int B, int L, int V) {
  int wave = threadIdx.x >> 6, lane = threadIdx.x & 63;
  int r = blockIdx.x * 4 + wave;
  if (r >= B * L * V) return;
  int b = r / (L * V), rem = r % (L * V), l = rem / V, u = rem % V;
  const float* h = hs + ((size_t)l * B + b) * H;
  const float* w = Wproj + (size_t)u * H;
  float a = 0.f;
  for (int k = lane; k < H; k += 64) a += h[k] * w[k];
  a = wsum(a);
  if (lane == 0) {
    a += bproj[u];
    int idx = (b * L + l) * V + u;
    logits[idx] = a;
    out_log[idx] = a;
  }
}

// ---------- w[b,v] = mean_l softmax(logits);  wb2[b,o] = sum_v w*b2 ----------
__global__ void k_wmix(const float* __restrict__ logits, const float* __restrict__ b2,
                       float* __restrict__ wv, float* __restrict__ wb2,
                       int B, int L, int V, int H) {
  __shared__ float sm[2048];
  __shared__ float wsh[512];
  int t = threadIdx.x;
  if (t < B * L) {
    const float* lg = logits + t * V;
    float mx = lg[0];
    for (int u = 1; u < V; u++) mx = fmaxf(mx, lg[u]);
    float s = 0.f;
    for (int u = 0; u < V; u++) s += expf(lg[u] - mx);
    for (int u = 0; u < V; u++) sm[t * V + u] = expf(lg[u] - mx) / s;
  }
  __syncthreads();
  if (t < B * V) {
    int b = t / V, u = t % V;
    float a = 0.f;
    for (int l = 0; l < L; l++) a += sm[(b * L + l) * V + u];
    a /= (float)L;
    wsh[t] = a;
    wv[t] = a;
  }
  __syncthreads();
  for (int idx = t; idx < B * H; idx += 256) {
    int b = idx / H, o = idx % H;
    float a = 0.f;
    for (int u = 0; u < V; u++) a += wsh[b * V + u] * b2[(size_t)u * H + o];
    wb2[idx] = a;
  }
}

// ---------- MFMA GEMM1: hmid[m,n] = wv[b,n/H]*gelu(x[m,:]·W1row(n)[:H] + b1[n] + feats·tail) ----------
// N = V*H; W1 row n has stride DIN (first H = matmul, last DC = tail folded in epilogue).
__global__ __launch_bounds__(256, 2) void gemm1_mfma(
    const float* __restrict__ A,      // x + moff*H
    const float* __restrict__ W1,     // row stride DIN
    bf16* __restrict__ hmid,          // chunk, ld = N
    const float* __restrict__ feats,  // BT x DC
    const float* __restrict__ b1,     // V*H
    const float* __restrict__ wv,     // B x V
    int rows, long moff, int H, int DIN, int DC, int N, int T, int V) {
  __shared__ __align__(16) bf16 As[128 * 32];
  __shared__ __align__(16) bf16 Bs[128 * 32];
  const int wave = threadIdx.x >> 6, lane = threadIdx.x & 63;
  const int m0 = blockIdx.y * 128, n0 = blockIdx.x * 128;
  const int mw = (wave >> 1) * 64, nw = (wave & 1) * 64;
  const int sRow = threadIdx.x >> 2, sK = (threadIdx.x & 3) * 8;
  const int rA = lane & 15, q8 = (lane >> 4) * 8;
  f32x4 acc[4][4];
#pragma unroll
  for (int i = 0; i < 4; i++)
#pragma unroll
    for (int j = 0; j < 4; j++) acc[i][j] = (f32x4){0.f, 0.f, 0.f, 0.f};

  int ar0 = m0 + sRow;      if (ar0 >= rows) ar0 = rows - 1;
  int ar1 = m0 + 64 + sRow; if (ar1 >= rows) ar1 = rows - 1;
  int br0 = n0 + sRow;      if (br0 >= N) br0 = N - 1;
  int br1 = n0 + 64 + sRow; if (br1 >= N) br1 = N - 1;
  const float* Ap0 = A + (size_t)ar0 * H + sK;
  const float* Ap1 = A + (size_t)ar1 * H + sK;
  const float* Bp0 = W1 + (size_t)br0 * DIN + sK;
  const float* Bp1 = W1 + (size_t)br1 * DIN + sK;

  for (int k0 = 0; k0 < H; k0 += 32) {
    bf16x8 a0 = cvt8(Ap0 + k0), a1 = cvt8(Ap1 + k0);
    bf16x8 b0 = cvt8(Bp0 + k0), b1r = cvt8(Bp1 + k0);
    __syncthreads();
    *(bf16x8*)&As[sRow * 32 + sK] = a0;
    *(bf16x8*)&As[(64 + sRow) * 32 + sK] = a1;
    *(bf16x8*)&Bs[sRow * 32 + sK] = b0;
    *(bf16x8*)&Bs[(64 + sRow) * 32 + sK] = b1r;
    __syncthreads();
    bf16x8 af[4], bf_[4];
#pragma unroll
    for (int i = 0; i < 4; i++) af[i] = *(const bf16x8*)&As[(mw + i * 16 + rA) * 32 + q8];
#pragma unroll
    for (int j = 0; j < 4; j++) bf_[j] = *(const bf16x8*)&Bs[(nw + j * 16 + rA) * 32 + q8];
#pragma unroll
    for (int i = 0; i < 4; i++)
#pragma unroll
      for (int j = 0; j < 4; j++)
        acc[i][j] = __builtin_amdgcn_mfma_f32_16x16x32_bf16(af[i], bf_[j], acc[i][j], 0, 0, 0);
  }

#pragma unroll
  for (int i = 0; i < 4; i++) {
#pragma unroll
    for (int r = 0; r < 4; r++) {
      int m = m0 + mw + i * 16 + (lane >> 4) * 4 + r;
      if (m >= rows) continue;
      long gm = moff + m;
      int b = (int)(gm / T);
      const float* fp = feats + (size_t)gm * DC;
#pragma unroll
      for (int j = 0; j < 4; j++) {
        int n = n0 + nw + j * 16 + rA;
        if (n >= N) continue;
        float val = acc[i][j][r] + b1[n];
        const float* tail = W1 + (size_t)n * DIN + H;
        for (int d = 0; d < DC; d++) val += fp[d] * tail[d];
        val = 0.5f * val * (1.0f + erff(val * 0.70710678118654752f));
        val *= wv[b * V + n / H];
        hmid[(size_t)m * N + n] = (bf16)val;
      }
    }
  }
}

// ---------- MFMA GEMM2: out[gm,n] = sum_k hmid[m,k]·W2[k/H][n][k%H] + wb2[b,n] ----------
__global__ __launch_bounds__(256, 2) void gemm2_mfma(
    const bf16* __restrict__ A,       // hmid chunk, ld = K (=V*H)
    const float* __restrict__ W2,     // (V,H,H)
    float* __restrict__ outY,
    const float* __restrict__ wb2,    // B x H
    int rows, long moff, int H, int K, int T) {
  __shared__ __align__(16) bf16 As[128 * 32];
  __shared__ __align__(16) bf16 Bs[128 * 32];
  const int wave = threadIdx.x >> 6, lane = threadIdx.x & 63;
  const int m0 = blockIdx.y * 128, n0 = blockIdx.x * 128;
  const int mw = (wave >> 1) * 64, nw = (wave & 1) * 64;
  const int sRow = threadIdx.x >> 2, sK = (threadIdx.x & 3) * 8;
  const int rA = lane & 15, q8 = (lane >> 4) * 8;
  f32x4 acc[4][4];
#pragma unroll
  for (int i = 0; i < 4; i++)
#pragma unroll
    for (int j = 0; j < 4; j++) acc[i][j] = (f32x4){0.f, 0.f, 0.f, 0.f};

  int ar0 = m0 + sRow;      if (ar0 >= rows) ar0 = rows - 1;
  int ar1 = m0 + 64 + sRow; if (ar1 >= rows) ar1 = rows - 1;
  int br0 = n0 + sRow;      if (br0 >= H) br0 = H - 1;
  int br1 = n0 + 64 + sRow; if (br1 >= H) br1 = H - 1;
  const bf16* Ap0 = A + (size_t)ar0 * K + sK;
  const bf16* Ap1 = A + (size_t)ar1 * K + sK;

  for (int k0 = 0; k0 < K; k0 += 32) {
    const float* Bk = W2 + (size_t)(k0 / H) * H * H + (k0 % H) + sK;
    bf16x8 a0 = *(const bf16x8*)(Ap0 + k0);
    bf16x8 a1 = *(const bf16x8*)(Ap1 + k0);
    bf16x8 b0 = cvt8(Bk + (size_t)br0 * H);
    bf16x8 b1r = cvt8(Bk + (size_t)br1 * H);
    __syncthreads();
    *(bf16x8*)&As[sRow * 32 + sK] = a0;
    *(bf16x8*)&As[(64 + sRow) * 32 + sK] = a1;
    *(bf16x8*)&Bs[sRow * 32 + sK] = b0;
    *(bf16x8*)&Bs[(64 + sRow) * 32 + sK] = b1r;
    __syncthreads();
    bf16x8 af[4], bf_[4];
#pragma unroll
    for (int i = 0; i < 4; i++) af[i] = *(const bf16x8*)&As[(mw + i * 16 + rA) * 32 + q8];
#pragma unroll
    for (int j = 0; j < 4; j++) bf_[j] = *(const bf16x8*)&Bs[(nw + j * 16 + rA) * 32 + q8];
#pragma unroll
    for (int i = 0; i < 4; i++)
#pragma unroll
      for (int j = 0; j < 4; j++)
        acc[i][j] = __builtin_amdgcn_mfma_f32_16x16x32_bf16(af[i], bf_[j], acc[i][j], 0, 0, 0);
  }

#pragma unroll
  for (int i = 0; i < 4; i++) {
#pragma unroll
    for (int r = 0; r < 4; r++) {
      int m = m0 + mw + i * 16 + (lane >> 4) * 4 + r;
      if (m >= rows) continue;
      long gm = moff + m;
      int b = (int)(gm / T);
#pragma unroll
      for (int j = 0; j < 4; j++) {
        int n = n0 + nw + j * 16 + rA;
        if (n >= H) continue;
        outY[(size_t)gm * H + n] = acc[i][j][r] + wb2[(size_t)b * H + n];
      }
    }
  }
}

extern "C" void kernel_launch(void* const* d_in, const int* in_sizes, int n_in,
                              void* d_out, int out_size, void* d_ws, size_t ws_size,
                              hipStream_t stream) {
  const float* x      = (const float*)d_in[0];
  const float* W_tt   = (const float*)d_in[1];
  const float* b_tt   = (const float*)d_in[2];
  const float* W_pol  = (const float*)d_in[3];
  const float* b_pol  = (const float*)d_in[4];
  const float* W_c2h  = (const float*)d_in[5];
  const float* b_c2h  = (const float*)d_in[6];
  const float* W_hh   = (const float*)d_in[8];
  const float* b_ih   = (const float*)d_in[9];
  const float* b_hh   = (const float*)d_in[10];
  const float* W_proj = (const float*)d_in[11];
  const float* b_proj = (const float*)d_in[12];
  const float* W1     = (const float*)d_in[13];
  const float* b1     = (const float*)d_in[14];
  const float* W2     = (const float*)d_in[15];
  const float* b2     = (const float*)d_in[16];
  float* out = (float*)d_out;
  char* ws = (char*)d_ws;

  // ---- derive dimensions ----
  const int C1 = in_sizes[2];
  const int C2 = in_sizes[4];
  const int H  = in_sizes[1] / C1;
  const int DC = C1 + C2;
  const int DIN = H + DC;
  const int V  = in_sizes[12];
  const long BT = (long)in_sizes[0] / H;
  long R = (long)out_size - BT * (long)(H + DC);
  int B = 0, L = 0;
  for (int Lc = 1; Lc <= 32; ++Lc) {
    long den = (long)Lc * V + H;
    if (R % den == 0) {
      long Bc = R / den;
      if (Bc >= 1 && BT % Bc == 0) {
        if (B == 0 || Lc == 4) { B = (int)Bc; L = Lc; }
        if (Lc == 4) break;
      }
    }
  }
  if (B == 0) { B = 8; L = 4; }
  const int T = (int)(BT / B);
  const long N2 = (long)V * H;

  // ---- workspace layout: small buffers first, hmid takes the remainder ----
  size_t o = 0;
  auto alloc = [&](size_t bytes) { size_t r = o; o = (o + bytes + 255) & ~(size_t)255; return r; };
  float* feats  = (float*)(ws + alloc((size_t)BT * DC * 4));
  size_t off_pooled = alloc((size_t)B * H * 4);
  float* pooled = (float*)(ws + off_pooled);
  size_t off_fsum = alloc((size_t)B * DC * 4);
  float* fsum   = (float*)(ws + off_fsum);
  float* hbuf   = (float*)(ws + alloc((size_t)2 * B * H * 4));
  float* hs     = (float*)(ws + alloc((size_t)L * B * H * 4));
  float* logits = (float*)(ws + alloc((size_t)B * L * V * 4));
  float* wv     = (float*)(ws + alloc((size_t)B * V * 4));
  float* wb2    = (float*)(ws + alloc((size_t)B * H * 4));
  size_t off_hmid = alloc(0);
  long avail = (long)ws_size - (long)off_hmid;
  long mcMax = avail / (N2 * 2);
  long Mc = (mcMax / 128) * 128;
  long bt128 = ((BT + 127) / 128) * 128;
  if (Mc > bt128) Mc = bt128;
  if (Mc < 128) Mc = 128;   // ws >= ~5.2 MB observed (round 8 passed); 128 rows = 2.1 MB
  bf16* hmid = (bf16*)(ws + off_hmid);

  // ---- output layout ----
  float* out_y    = out;
  float* out_log  = out_y + (size_t)BT * H;
  float* out_tt   = out_log + (size_t)B * L * V;
  float* out_pol  = out_tt + (size_t)BT * C1;
  float* out_pool = out_pol + (size_t)BT * C2;

  // zero pooled + fsum (contiguous range)
  hipMemsetAsync(ws + off_pooled, 0, off_fsum - off_pooled + (size_t)B * DC * 4, stream);

  k_feats<<<(int)((BT + 3) / 4), 256, 0, stream>>>(x, W_tt, b_tt, W_pol, b_pol,
                                                   out_tt, out_pol, feats, fsum,
                                                   H, T, (int)BT, C1, C2);
  int hBlocks = (H + 255) / 256;
  k_pool<<<B * hBlocks * 8, 256, 0, stream>>>(x, pooled, H, T, 8);
  k_ctx_h0<<<(B * H + 3) / 4, 256, 0, stream>>>(W_c2h, b_c2h, pooled, fsum,
                                                hbuf, out_pool, H, DIN, B, DC);
  float* hA = hbuf;
  float* hB = hbuf + (size_t)B * H;
  for (int l = 0; l < L; ++l) {
    k_gru<<<(B * H + 3) / 4, 256, 0, stream>>>((l & 1) ? hB : hA, W_hh, b_ih, b_hh,
                                               (l & 1) ? hA : hB, hs + (size_t)l * B * H,
                                               H, B);
  }
  k_logits<<<(B * L * V + 3) / 4, 256, 0, stream>>>(hs, W_proj, b_proj, logits,
                                                    out_log, H, B, L, V);
  k_wmix<<<1, 256, 0, stream>>>(logits, b2, wv, wb2, B, L, V, H);

  for (long moff = 0; moff < BT; moff += Mc) {
    int rows = (int)(((BT - moff) < Mc) ? (BT - moff) : Mc);
    dim3 g1((unsigned)((N2 + 127) / 128), (unsigned)((rows + 127) / 128));
    dim3 g2((unsigned)((H + 127) / 128), (unsigned)((rows + 127) / 128));
    gemm1_mfma<<<g1, 256, 0, stream>>>(x + (size_t)moff * H, W1, hmid, feats, b1, wv,
                                       rows, moff, H, DIN, DC, (int)N2, T, V);
    gemm2_mfma<<<g2, 256, 0, stream>>>(hmid, W2, out_y, wb2,
                                       rows, moff, H, (int)N2, T);
  }
}

// Round 10
// 1240.394 us; speedup vs baseline: 5.0630x; 1.1221x over previous
//
#include <hip/hip_runtime.h>
#include <hip/hip_bf16.h>
#include <math.h>

typedef __bf16 bf16;
typedef __bf16 bf16x8 __attribute__((ext_vector_type(8)));
typedef float f32x4 __attribute__((ext_vector_type(4)));

// Dims derived at runtime. Inputs f32, outputs f32.
// Outputs: out(B,T,H), logits(B,L,V), tt(B,T,C1), pol(B,T,C2), pooled(B,H).

__device__ __forceinline__ float wsum(float v) {
#pragma unroll
  for (int off = 32; off; off >>= 1) v += __shfl_xor(v, off, 64);
  return v;
}

__device__ __forceinline__ void g2l16(const bf16* g, bf16* l) {
  __builtin_amdgcn_global_load_lds(
      (__attribute__((address_space(1))) void*)g,
      (__attribute__((address_space(3))) void*)l, 16, 0, 0);
}

__device__ __forceinline__ bf16x8 pack8(float4 a, float4 b) {
  bf16x8 r;
  r[0] = (bf16)a.x; r[1] = (bf16)a.y; r[2] = (bf16)a.z; r[3] = (bf16)a.w;
  r[4] = (bf16)b.x; r[5] = (bf16)b.y; r[6] = (bf16)b.z; r[7] = (bf16)b.w;
  return r;
}

// ---------- f32 -> bf16 bulk convert (n must allow 8-wide main loop; tail scalar) ----------
__global__ void k_cvt(const float* __restrict__ s, bf16* __restrict__ d, long n) {
  long stride = (long)gridDim.x * blockDim.x;
  for (long i = (long)blockIdx.x * blockDim.x + threadIdx.x; i * 8 < n; i += stride) {
    long e = i * 8;
    if (e + 8 <= n) {
      float4 a = *(const float4*)(s + e);
      float4 b = *(const float4*)(s + e + 4);
      *(bf16x8*)(d + e) = pack8(a, b);
    } else {
      for (long j = e; j < n; j++) d[j] = (bf16)s[j];
    }
  }
}

// ---------- strip W1's matmul part (first H of each DIN-stride row) to bf16 ----------
__global__ void k_cvt_w1(const float* __restrict__ W1, bf16* __restrict__ W1b,
                         int H, int DIN, long N2) {
  long total8 = ((long)N2 * H) / 8;
  long stride = (long)gridDim.x * blockDim.x;
  for (long i = (long)blockIdx.x * blockDim.x + threadIdx.x; i < total8; i += stride) {
    long e = i * 8;
    long n = e / H;
    int h = (int)(e % H);
    const float* p = W1 + n * DIN + h;
    float4 a = *(const float4*)p;
    float4 b = *(const float4*)(p + 4);
    *(bf16x8*)(W1b + e) = pack8(a, b);
  }
}

// ---------- concept feats ----------
__global__ void k_feats(const float* __restrict__ x,
                        const float* __restrict__ Wtt, const float* __restrict__ btt,
                        const float* __restrict__ Wpol, const float* __restrict__ bpol,
                        float* __restrict__ out_tt, float* __restrict__ out_pol,
                        float* __restrict__ feats, float* __restrict__ fsum,
                        int H, int T, int BT, int C1, int C2) {
  int wave = threadIdx.x >> 6, lane = threadIdx.x & 63;
  int site = blockIdx.x * 4 + wave;
  if (site >= BT) return;
  int DC = C1 + C2;
  int b = site / T;
  const float* xp = x + (size_t)site * H;
  const float* wp[16];
#pragma unroll
  for (int c = 0; c < 16; c++) {
    int cc = (c < DC) ? c : 0;
    wp[c] = (cc < C1) ? (Wtt + (size_t)cc * H) : (Wpol + (size_t)(cc - C1) * H);
  }
  float acc[16];
#pragma unroll
  for (int c = 0; c < 16; c++) acc[c] = 0.f;
  for (int k = lane; k < H; k += 64) {
    float xv = xp[k];
#pragma unroll
    for (int c = 0; c < 16; c++)
      if (c < DC) acc[c] += xv * wp[c][k];
  }
#pragma unroll
  for (int c = 0; c < 16; c++)
    if (c < DC) acc[c] = wsum(acc[c]);
  if (lane == 0) {
    for (int c = 0; c < DC; c++) {
      float val = acc[c] + (c < C1 ? btt[c] : bpol[c - C1]);
      if (c < C1) out_tt[(size_t)site * C1 + c] = val;
      else        out_pol[(size_t)site * C2 + (c - C1)] = val;
      feats[(size_t)site * DC + c] = val;
      atomicAdd(&fsum[b * DC + c], val / (float)T);
    }
  }
}

// ---------- pooled mean over T ----------
__global__ void k_pool(const float* __restrict__ x, float* __restrict__ pooled,
                       int H, int T, int tsplit) {
  int hBlocks = (H + 255) / 256;
  int bs = blockIdx.x / tsplit, ts = blockIdx.x % tsplit;
  int b = bs / hBlocks;
  int h = (bs % hBlocks) * 256 + threadIdx.x;
  if (h >= H) return;
  int tlo = (int)(((long)T * ts) / tsplit), thi = (int)(((long)T * (ts + 1)) / tsplit);
  const float* p = x + (size_t)b * T * H + h;
  float s = 0.f;
  for (int t = tlo; t < thi; t++) s += p[(size_t)t * H];
  atomicAdd(&pooled[(size_t)b * H + h], s / (float)T);
}

// ---------- context -> h0 ----------
__global__ void k_ctx_h0(const float* __restrict__ Wc2h, const float* __restrict__ bc2h,
                         const float* __restrict__ pooled, const float* __restrict__ fmean,
                         float* __restrict__ h0, float* __restrict__ out_pool,
                         int H, int DIN, int B, int DC) {
  int wave = threadIdx.x >> 6, lane = threadIdx.x & 63;
  int r = blockIdx.x * 4 + wave;
  if (r >= B * H) return;
  int b = r / H, j = r % H;
  const float* wrow = Wc2h + (size_t)j * DIN;
  float a = 0.f;
  for (int k = lane; k < DIN; k += 64) {
    float cv = (k < H) ? pooled[(size_t)b * H + k] : fmean[b * DC + (k - H)];
    a += cv * wrow[k];
  }
  a = wsum(a);
  if (lane == 0) {
    h0[r] = a + bc2h[j];
    out_pool[r] = pooled[r];
  }
}

// ---------- one GRU step ----------
__global__ void k_gru(const float* __restrict__ hin, const float* __restrict__ Whh,
                      const float* __restrict__ bih, const float* __restrict__ bhh,
                      float* __restrict__ hout, float* __restrict__ hsl,
                      int H, int B) {
  int wave = threadIdx.x >> 6, lane = threadIdx.x & 63;
  int r = blockIdx.x * 4 + wave;
  if (r >= B * H) return;
  int b = r / H, j = r % H;
  const float* h = hin + (size_t)b * H;
  const float* w0 = Whh + (size_t)j * H;
  const float* w1 = Whh + (size_t)(H + j) * H;
  const float* w2 = Whh + (size_t)(2 * H + j) * H;
  float ar = 0, az = 0, an = 0;
  for (int k = lane; k < H; k += 64) {
    float hv = h[k];
    ar += hv * w0[k];
    az += hv * w1[k];
    an += hv * w2[k];
  }
  ar = wsum(ar); az = wsum(az); an = wsum(an);
  if (lane == 0) {
    float ghr = ar + bhh[j];
    float ghz = az + bhh[H + j];
    float ghn = an + bhh[2 * H + j];
    float rg = 1.f / (1.f + expf(-(bih[j] + ghr)));
    float zg = 1.f / (1.f + expf(-(bih[H + j] + ghz)));
    float ng = tanhf(bih[2 * H + j] + rg * ghn);
    float hn = (1.f - zg) * ng + zg * h[j];
    hout[r] = hn;
    hsl[r] = hn;
  }
}

// ---------- program logits ----------
__global__ void k_logits(const float* __restrict__ hs, const float* __restrict__ Wproj,
                         const float* __restrict__ bproj, float* __restrict__ logits,
                         float* __restrict__ out_log, int H, int B, int L, int V) {
  int wave = threadIdx.x >> 6, lane = threadIdx.x & 63;
  int r = blockIdx.x * 4 + wave;
  if (r >= B * L * V) return;
  int b = r / (L * V), rem = r % (L * V), l = rem / V, u = rem % V;
  const float* h = hs + ((size_t)l * B + b) * H;
  const float* w = Wproj + (size_t)u * H;
  float a = 0.f;
  for (int k = lane; k < H; k += 64) a += h[k] * w[k];
  a = wsum(a);
  if (lane == 0) {
    a += bproj[u];
    int idx = (b * L + l) * V + u;
    logits[idx] = a;
    out_log[idx] = a;
  }
}

// ---------- w[b,v] = mean_l softmax(logits);  wb2[b,o] = sum_v w*b2 ----------
__global__ void k_wmix(const float* __restrict__ logits, const float* __restrict__ b2,
                       float* __restrict__ wv, float* __restrict__ wb2,
                       int B, int L, int V, int H) {
  __shared__ float sm[2048];
  __shared__ float wsh[512];
  int t = threadIdx.x;
  if (t < B * L) {
    const float* lg = logits + t * V;
    float mx = lg[0];
    for (int u = 1; u < V; u++) mx = fmaxf(mx, lg[u]);
    float s = 0.f;
    for (int u = 0; u < V; u++) s += expf(lg[u] - mx);
    for (int u = 0; u < V; u++) sm[t * V + u] = expf(lg[u] - mx) / s;
  }
  __syncthreads();
  if (t < B * V) {
    int b = t / V, u = t % V;
    float a = 0.f;
    for (int l = 0; l < L; l++) a += sm[(b * L + l) * V + u];
    a /= (float)L;
    wsh[t] = a;
    wv[t] = a;
  }
  __syncthreads();
  for (int idx = t; idx < B * H; idx += 256) {
    int b = idx / H, o = idx % H;
    float a = 0.f;
    for (int u = 0; u < V; u++) a += wsh[b * V + u] * b2[(size_t)u * H + o];
    wb2[idx] = a;
  }
}

// ---------- MFMA GEMM1 (m97 staging): hmid = wv*gelu(xb·W1b^T + b1 + feats·tail) ----------
__global__ __launch_bounds__(256, 2) void gemm1_mfma(
    const bf16* __restrict__ A,       // xb + moff*H
    const bf16* __restrict__ Bb,      // W1b, row stride H
    bf16* __restrict__ hmid,          // chunk, ld = N
    const float* __restrict__ W1,     // f32, row stride DIN (for tail)
    const float* __restrict__ feats,  // BT x DC
    const float* __restrict__ b1,     // V*H
    const float* __restrict__ wv,     // B x V
    int rows, long moff, int H, int DIN, int DC, int N, int T, int V) {
  __shared__ __align__(16) bf16 As[128 * 32];
  __shared__ __align__(16) bf16 Bs[128 * 32];
  const int wave = threadIdx.x >> 6, lane = threadIdx.x & 63;
  const int m0 = blockIdx.y * 128, n0 = blockIdx.x * 128;
  const int mw = (wave >> 1) * 64, nw = (wave & 1) * 64;
  const int sRow = lane >> 2, sK = (lane & 3) * 8;
  const int rA = lane & 15, q8 = (lane >> 4) * 8;
  f32x4 acc[4][4];
#pragma unroll
  for (int i = 0; i < 4; i++)
#pragma unroll
    for (int j = 0; j < 4; j++) acc[i][j] = (f32x4){0.f, 0.f, 0.f, 0.f};

  // per-lane staging rows (clamped); LDS dest is wave-uniform base + lane*16
  int arow[2], brow[2];
#pragma unroll
  for (int t = 0; t < 2; ++t) {
    int s = wave * 2 + t;
    int r = s * 16 + sRow;
    arow[t] = (m0 + r < rows) ? (m0 + r) : (rows - 1);
    brow[t] = (n0 + r < N) ? (n0 + r) : (N - 1);
  }

  for (int k0 = 0; k0 < H; k0 += 32) {
    __syncthreads();
#pragma unroll
    for (int t = 0; t < 2; ++t) {
      int s = wave * 2 + t;
      g2l16(A + (size_t)arow[t] * H + k0 + sK, &As[s * 512]);
      g2l16(Bb + (size_t)brow[t] * H + k0 + sK, &Bs[s * 512]);
    }
    __syncthreads();
    bf16x8 af[4], bf_[4];
#pragma unroll
    for (int i = 0; i < 4; i++) af[i] = *(const bf16x8*)&As[(mw + i * 16 + rA) * 32 + q8];
#pragma unroll
    for (int j = 0; j < 4; j++) bf_[j] = *(const bf16x8*)&Bs[(nw + j * 16 + rA) * 32 + q8];
#pragma unroll
    for (int i = 0; i < 4; i++)
#pragma unroll
      for (int j = 0; j < 4; j++)
        acc[i][j] = __builtin_amdgcn_mfma_f32_16x16x32_bf16(af[i], bf_[j], acc[i][j], 0, 0, 0);
  }

#pragma unroll
  for (int i = 0; i < 4; i++) {
#pragma unroll
    for (int r = 0; r < 4; r++) {
      int m = m0 + mw + i * 16 + (lane >> 4) * 4 + r;
      if (m >= rows) continue;
      long gm = moff + m;
      int b = (int)(gm / T);
      const float* fp = feats + (size_t)gm * DC;
#pragma unroll
      for (int j = 0; j < 4; j++) {
        int n = n0 + nw + j * 16 + rA;
        if (n >= N) continue;
        float val = acc[i][j][r] + b1[n];
        const float* tail = W1 + (size_t)n * DIN + H;
        for (int d = 0; d < DC; d++) val += fp[d] * tail[d];
        val = 0.5f * val * (1.0f + erff(val * 0.70710678118654752f));
        val *= wv[b * V + n / H];
        hmid[(size_t)m * N + n] = (bf16)val;
      }
    }
  }
}

// ---------- MFMA GEMM2 (m97 staging): out = hmid·W2b^T(v-blocked) + wb2 ----------
__global__ __launch_bounds__(256, 2) void gemm2_mfma(
    const bf16* __restrict__ A,       // hmid chunk, ld = K (=V*H)
    const bf16* __restrict__ W2b,     // (V,H,H) bf16
    float* __restrict__ outY,
    const float* __restrict__ wb2,    // B x H
    int rows, long moff, int H, int K, int T) {
  __shared__ __align__(16) bf16 As[128 * 32];
  __shared__ __align__(16) bf16 Bs[128 * 32];
  const int wave = threadIdx.x >> 6, lane = threadIdx.x & 63;
  const int m0 = blockIdx.y * 128, n0 = blockIdx.x * 128;
  const int mw = (wave >> 1) * 64, nw = (wave & 1) * 64;
  const int sRow = lane >> 2, sK = (lane & 3) * 8;
  const int rA = lane & 15, q8 = (lane >> 4) * 8;
  f32x4 acc[4][4];
#pragma unroll
  for (int i = 0; i < 4; i++)
#pragma unroll
    for (int j = 0; j < 4; j++) acc[i][j] = (f32x4){0.f, 0.f, 0.f, 0.f};

  int arow[2], brow[2];
#pragma unroll
  for (int t = 0; t < 2; ++t) {
    int s = wave * 2 + t;
    int r = s * 16 + sRow;
    arow[t] = (m0 + r < rows) ? (m0 + r) : (rows - 1);
    brow[t] = (n0 + r < H) ? (n0 + r) : (H - 1);
  }

  int kv = 0, kh = 0;
  for (int k0 = 0; k0 < K; k0 += 32) {
    const bf16* Bk = W2b + (size_t)kv * H * H + kh;
    __syncthreads();
#pragma unroll
    for (int t = 0; t < 2; ++t) {
      int s = wave * 2 + t;
      g2l16(A + (size_t)arow[t] * K + k0 + sK, &As[s * 512]);
      g2l16(Bk + (size_t)brow[t] * H + sK, &Bs[s * 512]);
    }
    __syncthreads();
    bf16x8 af[4], bf_[4];
#pragma unroll
    for (int i = 0; i < 4; i++) af[i] = *(const bf16x8*)&As[(mw + i * 16 + rA) * 32 + q8];
#pragma unroll
    for (int j = 0; j < 4; j++) bf_[j] = *(const bf16x8*)&Bs[(nw + j * 16 + rA) * 32 + q8];
#pragma unroll
    for (int i = 0; i < 4; i++)
#pragma unroll
      for (int j = 0; j < 4; j++)
        acc[i][j] = __builtin_amdgcn_mfma_f32_16x16x32_bf16(af[i], bf_[j], acc[i][j], 0, 0, 0);
    kh += 32;
    if (kh >= H) { kh = 0; kv++; }
  }

#pragma unroll
  for (int i = 0; i < 4; i++) {
#pragma unroll
    for (int r = 0; r < 4; r++) {
      int m = m0 + mw + i * 16 + (lane >> 4) * 4 + r;
      if (m >= rows) continue;
      long gm = moff + m;
      int b = (int)(gm / T);
#pragma unroll
      for (int j = 0; j < 4; j++) {
        int n = n0 + nw + j * 16 + rA;
        if (n >= H) continue;
        outY[(size_t)gm * H + n] = acc[i][j][r] + wb2[(size_t)b * H + n];
      }
    }
  }
}

extern "C" void kernel_launch(void* const* d_in, const int* in_sizes, int n_in,
                              void* d_out, int out_size, void* d_ws, size_t ws_size,
                              hipStream_t stream) {
  const float* x      = (const float*)d_in[0];
  const float* W_tt   = (const float*)d_in[1];
  const float* b_tt   = (const float*)d_in[2];
  const float* W_pol  = (const float*)d_in[3];
  const float* b_pol  = (const float*)d_in[4];
  const float* W_c2h  = (const float*)d_in[5];
  const float* b_c2h  = (const float*)d_in[6];
  const float* W_hh   = (const float*)d_in[8];
  const float* b_ih   = (const float*)d_in[9];
  const float* b_hh   = (const float*)d_in[10];
  const float* W_proj = (const float*)d_in[11];
  const float* b_proj = (const float*)d_in[12];
  const float* W1     = (const float*)d_in[13];
  const float* b1     = (const float*)d_in[14];
  const float* W2     = (const float*)d_in[15];
  const float* b2     = (const float*)d_in[16];
  float* out = (float*)d_out;
  char* ws = (char*)d_ws;

  // ---- derive dimensions ----
  const int C1 = in_sizes[2];
  const int C2 = in_sizes[4];
  const int H  = in_sizes[1] / C1;
  const int DC = C1 + C2;
  const int DIN = H + DC;
  const int V  = in_sizes[12];
  const long BT = (long)in_sizes[0] / H;
  long R = (long)out_size - BT * (long)(H + DC);
  int B = 0, L = 0;
  for (int Lc = 1; Lc <= 32; ++Lc) {
    long den = (long)Lc * V + H;
    if (R % den == 0) {
      long Bc = R / den;
      if (Bc >= 1 && BT % Bc == 0) {
        if (B == 0 || Lc == 4) { B = (int)Bc; L = Lc; }
        if (Lc == 4) break;
      }
    }
  }
  if (B == 0) { B = 8; L = 4; }
  const int T = (int)(BT / B);
  const long N2 = (long)V * H;

  // ---- workspace layout ----
  size_t o = 0;
  auto alloc = [&](size_t bytes) { size_t r = o; o = (o + bytes + 255) & ~(size_t)255; return r; };
  float* feats  = (float*)(ws + alloc((size_t)BT * DC * 4));
  size_t off_pooled = alloc((size_t)B * H * 4);
  float* pooled = (float*)(ws + off_pooled);
  size_t off_fsum = alloc((size_t)B * DC * 4);
  float* fsum   = (float*)(ws + off_fsum);
  float* hbuf   = (float*)(ws + alloc((size_t)2 * B * H * 4));
  float* hs     = (float*)(ws + alloc((size_t)L * B * H * 4));
  float* logits = (float*)(ws + alloc((size_t)B * L * V * 4));
  float* wv     = (float*)(ws + alloc((size_t)B * V * 4));
  float* wb2    = (float*)(ws + alloc((size_t)B * H * 4));
  bf16* xb  = (bf16*)(ws + alloc((size_t)BT * H * 2));
  bf16* W1b = (bf16*)(ws + alloc((size_t)N2 * H * 2));
  bf16* W2b = (bf16*)(ws + alloc((size_t)N2 * H * 2));
  size_t off_hmid = alloc(0);
  long avail = (long)ws_size - (long)off_hmid;
  long mcMax = avail / (N2 * 2);
  long Mc = (mcMax / 128) * 128;
  long bt128 = ((BT + 127) / 128) * 128;
  if (Mc > bt128) Mc = bt128;
  if (Mc < 128) Mc = 128;
  bf16* hmid = (bf16*)(ws + off_hmid);

  // ---- output layout ----
  float* out_y    = out;
  float* out_log  = out_y + (size_t)BT * H;
  float* out_tt   = out_log + (size_t)B * L * V;
  float* out_pol  = out_tt + (size_t)BT * C1;
  float* out_pool = out_pol + (size_t)BT * C2;

  hipMemsetAsync(ws + off_pooled, 0, off_fsum - off_pooled + (size_t)B * DC * 4, stream);

  // bulk converts
  k_cvt<<<2048, 256, 0, stream>>>(x, xb, BT * (long)H);
  k_cvt_w1<<<4096, 256, 0, stream>>>(W1, W1b, H, DIN, N2);
  k_cvt<<<4096, 256, 0, stream>>>(W2, W2b, N2 * (long)H);

  k_feats<<<(int)((BT + 3) / 4), 256, 0, stream>>>(x, W_tt, b_tt, W_pol, b_pol,
                                                   out_tt, out_pol, feats, fsum,
                                                   H, T, (int)BT, C1, C2);
  int hBlocks = (H + 255) / 256;
  k_pool<<<B * hBlocks * 8, 256, 0, stream>>>(x, pooled, H, T, 8);
  k_ctx_h0<<<(B * H + 3) / 4, 256, 0, stream>>>(W_c2h, b_c2h, pooled, fsum,
                                                hbuf, out_pool, H, DIN, B, DC);
  float* hA = hbuf;
  float* hB = hbuf + (size_t)B * H;
  for (int l = 0; l < L; ++l) {
    k_gru<<<(B * H + 3) / 4, 256, 0, stream>>>((l & 1) ? hB : hA, W_hh, b_ih, b_hh,
                                               (l & 1) ? hA : hB, hs + (size_t)l * B * H,
                                               H, B);
  }
  k_logits<<<(B * L * V + 3) / 4, 256, 0, stream>>>(hs, W_proj, b_proj, logits,
                                                    out_log, H, B, L, V);
  k_wmix<<<1, 256, 0, stream>>>(logits, b2, wv, wb2, B, L, V, H);

  for (long moff = 0; moff < BT; moff += Mc) {
    int rows = (int)(((BT - moff) < Mc) ? (BT - moff) : Mc);
    dim3 g1((unsigned)((N2 + 127) / 128), (unsigned)((rows + 127) / 128));
    dim3 g2((unsigned)((H + 127) / 128), (unsigned)((rows + 127) / 128));
    gemm1_mfma<<<g1, 256, 0, stream>>>(xb + (size_t)moff * H, W1b, hmid, W1, feats, b1, wv,
                                       rows, moff, H, DIN, DC, (int)N2, T, V);
    gemm2_mfma<<<g2, 256, 0, stream>>>(hmid, W2b, out_y, wb2,
                                       rows, moff, H, (int)N2, T);
  }
}

// Round 11
// 786.056 us; speedup vs baseline: 7.9895x; 1.5780x over previous
//
#include <hip/hip_runtime.h>
#include <hip/hip_bf16.h>
#include <math.h>

typedef __bf16 bf16;
typedef __bf16 bf16x8 __attribute__((ext_vector_type(8)));
typedef float f32x4 __attribute__((ext_vector_type(4)));

// Dims derived at runtime. Inputs f32, outputs f32.
// Outputs: out(B,T,H), logits(B,L,V), tt(B,T,C1), pol(B,T,C2), pooled(B,H).
// GEMM1 K-extension: KE = H+32, last 32 cols = [feats|0] (A) and [W1 tail|0] (B),
// so the concept-feat rank-DC term rides inside the MFMA accumulation.

__device__ __forceinline__ float wsum(float v) {
#pragma unroll
  for (int off = 32; off; off >>= 1) v += __shfl_xor(v, off, 64);
  return v;
}

__device__ __forceinline__ void g2l16(const bf16* g, bf16* l) {
  __builtin_amdgcn_global_load_lds(
      (__attribute__((address_space(1))) void*)g,
      (__attribute__((address_space(3))) void*)l, 16, 0, 0);
}

__device__ __forceinline__ bf16x8 pack8(float4 a, float4 b) {
  bf16x8 r;
  r[0] = (bf16)a.x; r[1] = (bf16)a.y; r[2] = (bf16)a.z; r[3] = (bf16)a.w;
  r[4] = (bf16)b.x; r[5] = (bf16)b.y; r[6] = (bf16)b.z; r[7] = (bf16)b.w;
  return r;
}

// ---------- f32 -> bf16 bulk convert (contiguous) ----------
__global__ void k_cvt(const float* __restrict__ s, bf16* __restrict__ d, long n) {
  long stride = (long)gridDim.x * blockDim.x;
  for (long i = (long)blockIdx.x * blockDim.x + threadIdx.x; i * 8 < n; i += stride) {
    long e = i * 8;
    if (e + 8 <= n) {
      float4 a = *(const float4*)(s + e);
      float4 b = *(const float4*)(s + e + 4);
      *(bf16x8*)(d + e) = pack8(a, b);
    } else {
      for (long j = e; j < n; j++) d[j] = (bf16)s[j];
    }
  }
}

// ---------- build xbE: row m = [cvt(x[m,:H]) | feats[m,:DC] | zeros] (ld = KE) ----------
__global__ void k_xext(const float* __restrict__ x, const float* __restrict__ feats,
                       bf16* __restrict__ xbE, int H, int KE, int DC, long BT) {
  int wave = threadIdx.x >> 6, lane = threadIdx.x & 63;
  long m = (long)blockIdx.x * 4 + wave;
  if (m >= BT) return;
  const float* xp = x + m * H;
  bf16* dp = xbE + m * KE;
  for (int e = lane * 8; e + 8 <= H; e += 512) {
    float4 a = *(const float4*)(xp + e);
    float4 b = *(const float4*)(xp + e + 4);
    *(bf16x8*)(dp + e) = pack8(a, b);
  }
  int pad = KE - H;
  if (lane < pad)
    dp[H + lane] = (lane < DC) ? (bf16)feats[m * DC + lane] : (bf16)0.f;
}

// ---------- build W1bE: row n = [cvt(W1[n,:H]) | cvt(W1[n,H:H+DC]) | zeros] ----------
__global__ void k_w1ext(const float* __restrict__ W1, bf16* __restrict__ W1bE,
                        int H, int DIN, int KE, int DC, long N2) {
  int wave = threadIdx.x >> 6, lane = threadIdx.x & 63;
  long n = (long)blockIdx.x * 4 + wave;
  if (n >= N2) return;
  const float* sp = W1 + n * DIN;
  bf16* dp = W1bE + n * KE;
  for (int e = lane * 8; e + 8 <= H; e += 512) {
    float4 a = *(const float4*)(sp + e);
    float4 b = *(const float4*)(sp + e + 4);
    *(bf16x8*)(dp + e) = pack8(a, b);
  }
  int pad = KE - H;
  if (lane < pad)
    dp[H + lane] = (lane < DC) ? (bf16)sp[H + lane] : (bf16)0.f;
}

// ---------- seed out_y with wb2 (broadcast over T); atomics accumulate on top ----------
__global__ void k_init(float* __restrict__ outY, const float* __restrict__ wb2,
                       int H, int T, long BT) {
  int wave = threadIdx.x >> 6, lane = threadIdx.x & 63;
  long gm = (long)blockIdx.x * 4 + wave;
  if (gm >= BT) return;
  int b = (int)(gm / T);
  const float* s = wb2 + (size_t)b * H;
  float* d = outY + gm * H;
  for (int e = lane * 4; e + 4 <= H; e += 256)
    *(float4*)(d + e) = *(const float4*)(s + e);
}

// ---------- concept feats ----------
__global__ void k_feats(const float* __restrict__ x,
                        const float* __restrict__ Wtt, const float* __restrict__ btt,
                        const float* __restrict__ Wpol, const float* __restrict__ bpol,
                        float* __restrict__ out_tt, float* __restrict__ out_pol,
                        float* __restrict__ feats, float* __restrict__ fsum,
                        int H, int T, int BT, int C1, int C2) {
  int wave = threadIdx.x >> 6, lane = threadIdx.x & 63;
  int site = blockIdx.x * 4 + wave;
  if (site >= BT) return;
  int DC = C1 + C2;
  int b = site / T;
  const float* xp = x + (size_t)site * H;
  const float* wp[16];
#pragma unroll
  for (int c = 0; c < 16; c++) {
    int cc = (c < DC) ? c : 0;
    wp[c] = (cc < C1) ? (Wtt + (size_t)cc * H) : (Wpol + (size_t)(cc - C1) * H);
  }
  float acc[16];
#pragma unroll
  for (int c = 0; c < 16; c++) acc[c] = 0.f;
  for (int k = lane; k < H; k += 64) {
    float xv = xp[k];
#pragma unroll
    for (int c = 0; c < 16; c++)
      if (c < DC) acc[c] += xv * wp[c][k];
  }
#pragma unroll
  for (int c = 0; c < 16; c++)
    if (c < DC) acc[c] = wsum(acc[c]);
  if (lane == 0) {
    for (int c = 0; c < DC; c++) {
      float val = acc[c] + (c < C1 ? btt[c] : bpol[c - C1]);
      if (c < C1) out_tt[(size_t)site * C1 + c] = val;
      else        out_pol[(size_t)site * C2 + (c - C1)] = val;
      feats[(size_t)site * DC + c] = val;
      atomicAdd(&fsum[b * DC + c], val / (float)T);
    }
  }
}

// ---------- pooled mean over T ----------
__global__ void k_pool(const float* __restrict__ x, float* __restrict__ pooled,
                       int H, int T, int tsplit) {
  int hBlocks = (H + 255) / 256;
  int bs = blockIdx.x / tsplit, ts = blockIdx.x % tsplit;
  int b = bs / hBlocks;
  int h = (bs % hBlocks) * 256 + threadIdx.x;
  if (h >= H) return;
  int tlo = (int)(((long)T * ts) / tsplit), thi = (int)(((long)T * (ts + 1)) / tsplit);
  const float* p = x + (size_t)b * T * H + h;
  float s = 0.f;
  for (int t = tlo; t < thi; t++) s += p[(size_t)t * H];
  atomicAdd(&pooled[(size_t)b * H + h], s / (float)T);
}

// ---------- context -> h0 ----------
__global__ void k_ctx_h0(const float* __restrict__ Wc2h, const float* __restrict__ bc2h,
                         const float* __restrict__ pooled, const float* __restrict__ fmean,
                         float* __restrict__ h0, float* __restrict__ out_pool,
                         int H, int DIN, int B, int DC) {
  int wave = threadIdx.x >> 6, lane = threadIdx.x & 63;
  int r = blockIdx.x * 4 + wave;
  if (r >= B * H) return;
  int b = r / H, j = r % H;
  const float* wrow = Wc2h + (size_t)j * DIN;
  float a = 0.f;
  for (int k = lane; k < DIN; k += 64) {
    float cv = (k < H) ? pooled[(size_t)b * H + k] : fmean[b * DC + (k - H)];
    a += cv * wrow[k];
  }
  a = wsum(a);
  if (lane == 0) {
    h0[r] = a + bc2h[j];
    out_pool[r] = pooled[r];
  }
}

// ---------- one GRU step ----------
__global__ void k_gru(const float* __restrict__ hin, const float* __restrict__ Whh,
                      const float* __restrict__ bih, const float* __restrict__ bhh,
                      float* __restrict__ hout, float* __restrict__ hsl,
                      int H, int B) {
  int wave = threadIdx.x >> 6, lane = threadIdx.x & 63;
  int r = blockIdx.x * 4 + wave;
  if (r >= B * H) return;
  int b = r / H, j = r % H;
  const float* h = hin + (size_t)b * H;
  const float* w0 = Whh + (size_t)j * H;
  const float* w1 = Whh + (size_t)(H + j) * H;
  const float* w2 = Whh + (size_t)(2 * H + j) * H;
  float ar = 0, az = 0, an = 0;
  for (int k = lane; k < H; k += 64) {
    float hv = h[k];
    ar += hv * w0[k];
    az += hv * w1[k];
    an += hv * w2[k];
  }
  ar = wsum(ar); az = wsum(az); an = wsum(an);
  if (lane == 0) {
    float ghr = ar + bhh[j];
    float ghz = az + bhh[H + j];
    float ghn = an + bhh[2 * H + j];
    float rg = 1.f / (1.f + expf(-(bih[j] + ghr)));
    float zg = 1.f / (1.f + expf(-(bih[H + j] + ghz)));
    float ng = tanhf(bih[2 * H + j] + rg * ghn);
    float hn = (1.f - zg) * ng + zg * h[j];
    hout[r] = hn;
    hsl[r] = hn;
  }
}

// ---------- program logits ----------
__global__ void k_logits(const float* __restrict__ hs, const float* __restrict__ Wproj,
                         const float* __restrict__ bproj, float* __restrict__ logits,
                         float* __restrict__ out_log, int H, int B, int L, int V) {
  int wave = threadIdx.x >> 6, lane = threadIdx.x & 63;
  int r = blockIdx.x * 4 + wave;
  if (r >= B * L * V) return;
  int b = r / (L * V), rem = r % (L * V), l = rem / V, u = rem % V;
  const float* h = hs + ((size_t)l * B + b) * H;
  const float* w = Wproj + (size_t)u * H;
  float a = 0.f;
  for (int k = lane; k < H; k += 64) a += h[k] * w[k];
  a = wsum(a);
  if (lane == 0) {
    a += bproj[u];
    int idx = (b * L + l) * V + u;
    logits[idx] = a;
    out_log[idx] = a;
  }
}

// ---------- w[b,v] = mean_l softmax(logits);  wb2[b,o] = sum_v w*b2 ----------
__global__ void k_wmix(const float* __restrict__ logits, const float* __restrict__ b2,
                       float* __restrict__ wv, float* __restrict__ wb2,
                       int B, int L, int V, int H) {
  __shared__ float sm[2048];
  __shared__ float wsh[512];
  int t = threadIdx.x;
  if (t < B * L) {
    const float* lg = logits + t * V;
    float mx = lg[0];
    for (int u = 1; u < V; u++) mx = fmaxf(mx, lg[u]);
    float s = 0.f;
    for (int u = 0; u < V; u++) s += expf(lg[u] - mx);
    for (int u = 0; u < V; u++) sm[t * V + u] = expf(lg[u] - mx) / s;
  }
  __syncthreads();
  if (t < B * V) {
    int b = t / V, u = t % V;
    float a = 0.f;
    for (int l = 0; l < L; l++) a += sm[(b * L + l) * V + u];
    a /= (float)L;
    wsh[t] = a;
    wv[t] = a;
  }
  __syncthreads();
  for (int idx = t; idx < B * H; idx += 256) {
    int b = idx / H, o = idx % H;
    float a = 0.f;
    for (int u = 0; u < V; u++) a += wsh[b * V + u] * b2[(size_t)u * H + o];
    wb2[idx] = a;
  }
}

// ---------- MFMA GEMM1: hmid = wv * gelu(xbE·W1bE^T + b1)  (tail folded into K) ----------
__global__ __launch_bounds__(256, 2) void gemm1_mfma(
    const bf16* __restrict__ A,       // xbE + moff*KE, ld = KE
    const bf16* __restrict__ Bb,      // W1bE, ld = KE
    bf16* __restrict__ hmid,          // chunk, ld = N
    const float* __restrict__ b1,     // V*H
    const float* __restrict__ wv,     // B x V
    int rows, long moff, int KE, int H, int N, int T, int V) {
  __shared__ __align__(16) bf16 As[128 * 32];
  __shared__ __align__(16) bf16 Bs[128 * 32];
  const int wave = threadIdx.x >> 6, lane = threadIdx.x & 63;
  const int m0 = blockIdx.y * 128, n0 = blockIdx.x * 128;
  const int mw = (wave >> 1) * 64, nw = (wave & 1) * 64;
  const int sRow = lane >> 2, sK = (lane & 3) * 8;
  const int rA = lane & 15, q8 = (lane >> 4) * 8;
  f32x4 acc[4][4];
#pragma unroll
  for (int i = 0; i < 4; i++)
#pragma unroll
    for (int j = 0; j < 4; j++) acc[i][j] = (f32x4){0.f, 0.f, 0.f, 0.f};

  int arow[2], brow[2];
#pragma unroll
  for (int t = 0; t < 2; ++t) {
    int s = wave * 2 + t;
    int r = s * 16 + sRow;
    arow[t] = (m0 + r < rows) ? (m0 + r) : (rows - 1);
    brow[t] = (n0 + r < N) ? (n0 + r) : (N - 1);
  }

  for (int k0 = 0; k0 < KE; k0 += 32) {
    __syncthreads();
#pragma unroll
    for (int t = 0; t < 2; ++t) {
      int s = wave * 2 + t;
      g2l16(A + (size_t)arow[t] * KE + k0 + sK, &As[s * 512]);
      g2l16(Bb + (size_t)brow[t] * KE + k0 + sK, &Bs[s * 512]);
    }
    __syncthreads();
    bf16x8 af[4], bf_[4];
#pragma unroll
    for (int i = 0; i < 4; i++) af[i] = *(const bf16x8*)&As[(mw + i * 16 + rA) * 32 + q8];
#pragma unroll
    for (int j = 0; j < 4; j++) bf_[j] = *(const bf16x8*)&Bs[(nw + j * 16 + rA) * 32 + q8];
#pragma unroll
    for (int i = 0; i < 4; i++)
#pragma unroll
      for (int j = 0; j < 4; j++)
        acc[i][j] = __builtin_amdgcn_mfma_f32_16x16x32_bf16(af[i], bf_[j], acc[i][j], 0, 0, 0);
  }

  // hoisted per-j column info
  int ncol[4], vj[4];
  float b1j[4];
#pragma unroll
  for (int j = 0; j < 4; j++) {
    int n = n0 + nw + j * 16 + rA;
    if (n >= N) n = N - 1;
    ncol[j] = n;
    vj[j] = n / H;
    b1j[j] = b1[n];
  }
#pragma unroll
  for (int i = 0; i < 4; i++) {
#pragma unroll
    for (int r = 0; r < 4; r++) {
      int m = m0 + mw + i * 16 + (lane >> 4) * 4 + r;
      if (m >= rows) continue;
      long gm = moff + m;
      int b = (int)(gm / T);
#pragma unroll
      for (int j = 0; j < 4; j++) {
        int n = n0 + nw + j * 16 + rA;
        if (n >= N) continue;
        float val = acc[i][j][r] + b1j[j];
        val = 0.5f * val * (1.0f + erff(val * 0.70710678118654752f));
        val *= wv[b * V + vj[j]];
        hmid[(size_t)m * N + n] = (bf16)val;
      }
    }
  }
}

// ---------- MFMA GEMM2 (K-split x ZS, atomic accumulate): out += hmid·W2b^T ----------
__global__ __launch_bounds__(256, 2) void gemm2_mfma(
    const bf16* __restrict__ A,       // hmid chunk, ld = K (=V*H)
    const bf16* __restrict__ W2b,     // (V,H,H) bf16
    float* __restrict__ outY,
    int rows, long moff, int H, int K, int T, int kchunk) {
  __shared__ __align__(16) bf16 As[128 * 32];
  __shared__ __align__(16) bf16 Bs[128 * 32];
  const int wave = threadIdx.x >> 6, lane = threadIdx.x & 63;
  const int m0 = blockIdx.y * 128, n0 = blockIdx.x * 128;
  const int mw = (wave >> 1) * 64, nw = (wave & 1) * 64;
  const int sRow = lane >> 2, sK = (lane & 3) * 8;
  const int rA = lane & 15, q8 = (lane >> 4) * 8;
  int kz0 = blockIdx.z * kchunk;
  int kz1 = kz0 + kchunk; if (kz1 > K) kz1 = K;
  if (kz0 >= K) return;
  f32x4 acc[4][4];
#pragma unroll
  for (int i = 0; i < 4; i++)
#pragma unroll
    for (int j = 0; j < 4; j++) acc[i][j] = (f32x4){0.f, 0.f, 0.f, 0.f};

  int arow[2], brow[2];
#pragma unroll
  for (int t = 0; t < 2; ++t) {
    int s = wave * 2 + t;
    int r = s * 16 + sRow;
    arow[t] = (m0 + r < rows) ? (m0 + r) : (rows - 1);
    brow[t] = (n0 + r < H) ? (n0 + r) : (H - 1);
  }

  int kv = kz0 / H, kh = kz0 % H;
  for (int k0 = kz0; k0 < kz1; k0 += 32) {
    const bf16* Bk = W2b + (size_t)kv * H * H + kh;
    __syncthreads();
#pragma unroll
    for (int t = 0; t < 2; ++t) {
      int s = wave * 2 + t;
      g2l16(A + (size_t)arow[t] * K + k0 + sK, &As[s * 512]);
      g2l16(Bk + (size_t)brow[t] * H + sK, &Bs[s * 512]);
    }
    __syncthreads();
    bf16x8 af[4], bf_[4];
#pragma unroll
    for (int i = 0; i < 4; i++) af[i] = *(const bf16x8*)&As[(mw + i * 16 + rA) * 32 + q8];
#pragma unroll
    for (int j = 0; j < 4; j++) bf_[j] = *(const bf16x8*)&Bs[(nw + j * 16 + rA) * 32 + q8];
#pragma unroll
    for (int i = 0; i < 4; i++)
#pragma unroll
      for (int j = 0; j < 4; j++)
        acc[i][j] = __builtin_amdgcn_mfma_f32_16x16x32_bf16(af[i], bf_[j], acc[i][j], 0, 0, 0);
    kh += 32;
    if (kh >= H) { kh = 0; kv++; }
  }

#pragma unroll
  for (int i = 0; i < 4; i++) {
#pragma unroll
    for (int r = 0; r < 4; r++) {
      int m = m0 + mw + i * 16 + (lane >> 4) * 4 + r;
      if (m >= rows) continue;
      long gm = moff + m;
#pragma unroll
      for (int j = 0; j < 4; j++) {
        int n = n0 + nw + j * 16 + rA;
        if (n >= H) continue;
        atomicAdd(&outY[(size_t)gm * H + n], acc[i][j][r]);
      }
    }
  }
}

extern "C" void kernel_launch(void* const* d_in, const int* in_sizes, int n_in,
                              void* d_out, int out_size, void* d_ws, size_t ws_size,
                              hipStream_t stream) {
  const float* x      = (const float*)d_in[0];
  const float* W_tt   = (const float*)d_in[1];
  const float* b_tt   = (const float*)d_in[2];
  const float* W_pol  = (const float*)d_in[3];
  const float* b_pol  = (const float*)d_in[4];
  const float* W_c2h  = (const float*)d_in[5];
  const float* b_c2h  = (const float*)d_in[6];
  const float* W_hh   = (const float*)d_in[8];
  const float* b_ih   = (const float*)d_in[9];
  const float* b_hh   = (const float*)d_in[10];
  const float* W_proj = (const float*)d_in[11];
  const float* b_proj = (const float*)d_in[12];
  const float* W1     = (const float*)d_in[13];
  const float* b1     = (const float*)d_in[14];
  const float* W2     = (const float*)d_in[15];
  const float* b2     = (const float*)d_in[16];
  float* out = (float*)d_out;
  char* ws = (char*)d_ws;

  // ---- derive dimensions ----
  const int C1 = in_sizes[2];
  const int C2 = in_sizes[4];
  const int H  = in_sizes[1] / C1;
  const int DC = C1 + C2;
  const int DIN = H + DC;
  const int V  = in_sizes[12];
  const long BT = (long)in_sizes[0] / H;
  long R = (long)out_size - BT * (long)(H + DC);
  int B = 0, L = 0;
  for (int Lc = 1; Lc <= 32; ++Lc) {
    long den = (long)Lc * V + H;
    if (R % den == 0) {
      long Bc = R / den;
      if (Bc >= 1 && BT % Bc == 0) {
        if (B == 0 || Lc == 4) { B = (int)Bc; L = Lc; }
        if (Lc == 4) break;
      }
    }
  }
  if (B == 0) { B = 8; L = 4; }
  const int T = (int)(BT / B);
  const long N2 = (long)V * H;
  const int KE = H + 32;   // extended K (assumes H % 32 == 0; holds for this family)

  // ---- workspace layout ----
  size_t o = 0;
  auto alloc = [&](size_t bytes) { size_t r = o; o = (o + bytes + 255) & ~(size_t)255; return r; };
  float* feats  = (float*)(ws + alloc((size_t)BT * DC * 4));
  size_t off_pooled = alloc((size_t)B * H * 4);
  float* pooled = (float*)(ws + off_pooled);
  size_t off_fsum = alloc((size_t)B * DC * 4);
  float* fsum   = (float*)(ws + off_fsum);
  float* hbuf   = (float*)(ws + alloc((size_t)2 * B * H * 4));
  float* hs     = (float*)(ws + alloc((size_t)L * B * H * 4));
  float* logits = (float*)(ws + alloc((size_t)B * L * V * 4));
  float* wv     = (float*)(ws + alloc((size_t)B * V * 4));
  float* wb2    = (float*)(ws + alloc((size_t)B * H * 4));
  bf16* xbE  = (bf16*)(ws + alloc((size_t)BT * KE * 2));
  bf16* W1bE = (bf16*)(ws + alloc((size_t)N2 * KE * 2));
  bf16* W2b  = (bf16*)(ws + alloc((size_t)N2 * H * 2));
  size_t off_hmid = alloc(0);
  long avail = (long)ws_size - (long)off_hmid;
  long mcMax = avail / (N2 * 2);
  long Mc = (mcMax / 128) * 128;
  long bt128 = ((BT + 127) / 128) * 128;
  if (Mc > bt128) Mc = bt128;
  if (Mc < 128) Mc = 128;
  bf16* hmid = (bf16*)(ws + off_hmid);

  // ---- output layout ----
  float* out_y    = out;
  float* out_log  = out_y + (size_t)BT * H;
  float* out_tt   = out_log + (size_t)B * L * V;
  float* out_pol  = out_tt + (size_t)BT * C1;
  float* out_pool = out_pol + (size_t)BT * C2;

  hipMemsetAsync(ws + off_pooled, 0, off_fsum - off_pooled + (size_t)B * DC * 4, stream);

  k_cvt<<<4096, 256, 0, stream>>>(W2, W2b, N2 * (long)H);
  k_feats<<<(int)((BT + 3) / 4), 256, 0, stream>>>(x, W_tt, b_tt, W_pol, b_pol,
                                                   out_tt, out_pol, feats, fsum,
                                                   H, T, (int)BT, C1, C2);
  k_xext<<<(int)((BT + 3) / 4), 256, 0, stream>>>(x, feats, xbE, H, KE, DC, BT);
  k_w1ext<<<(int)((N2 + 3) / 4), 256, 0, stream>>>(W1, W1bE, H, DIN, KE, DC, N2);
  int hBlocks = (H + 255) / 256;
  k_pool<<<B * hBlocks * 8, 256, 0, stream>>>(x, pooled, H, T, 8);
  k_ctx_h0<<<(B * H + 3) / 4, 256, 0, stream>>>(W_c2h, b_c2h, pooled, fsum,
                                                hbuf, out_pool, H, DIN, B, DC);
  float* hA = hbuf;
  float* hB = hbuf + (size_t)B * H;
  for (int l = 0; l < L; ++l) {
    k_gru<<<(B * H + 3) / 4, 256, 0, stream>>>((l & 1) ? hB : hA, W_hh, b_ih, b_hh,
                                               (l & 1) ? hA : hB, hs + (size_t)l * B * H,
                                               H, B);
  }
  k_logits<<<(B * L * V + 3) / 4, 256, 0, stream>>>(hs, W_proj, b_proj, logits,
                                                    out_log, H, B, L, V);
  k_wmix<<<1, 256, 0, stream>>>(logits, b2, wv, wb2, B, L, V, H);
  k_init<<<(int)((BT + 3) / 4), 256, 0, stream>>>(out_y, wb2, H, T, BT);

  const int ZS = 4;
  int kchunk = (int)((((N2 / ZS) + 31) / 32) * 32);
  for (long moff = 0; moff < BT; moff += Mc) {
    int rows = (int)(((BT - moff) < Mc) ? (BT - moff) : Mc);
    dim3 g1((unsigned)((N2 + 127) / 128), (unsigned)((rows + 127) / 128));
    dim3 g2((unsigned)((H + 127) / 128), (unsigned)((rows + 127) / 128), ZS);
    gemm1_mfma<<<g1, 256, 0, stream>>>(xbE + (size_t)moff * KE, W1bE, hmid, b1, wv,
                                       rows, moff, KE, H, (int)N2, T, V);
    gemm2_mfma<<<g2, 256, 0, stream>>>(hmid, W2b, out_y,
                                       rows, moff, H, (int)N2, T, kchunk);
  }
}

// Round 12
// 765.084 us; speedup vs baseline: 8.2085x; 1.0274x over previous
//
#include <hip/hip_runtime.h>
#include <hip/hip_bf16.h>
#include <math.h>

typedef __bf16 bf16;
typedef __bf16 bf16x8 __attribute__((ext_vector_type(8)));
typedef float f32x4 __attribute__((ext_vector_type(4)));

// Dims derived at runtime. Inputs f32, outputs f32.
// Outputs: out(B,T,H), logits(B,L,V), tt(B,T,C1), pol(B,T,C2), pooled(B,H).
// GEMM1 K-extension: KE = H+32, last 32 cols = [feats|0] (A) and [W1 tail|0] (B).

__device__ __forceinline__ float wsum(float v) {
#pragma unroll
  for (int off = 32; off; off >>= 1) v += __shfl_xor(v, off, 64);
  return v;
}

__device__ __forceinline__ void g2l16(const bf16* g, bf16* l) {
  __builtin_amdgcn_global_load_lds(
      (__attribute__((address_space(1))) void*)g,
      (__attribute__((address_space(3))) void*)l, 16, 0, 0);
}

__device__ __forceinline__ bf16x8 pack8(float4 a, float4 b) {
  bf16x8 r;
  r[0] = (bf16)a.x; r[1] = (bf16)a.y; r[2] = (bf16)a.z; r[3] = (bf16)a.w;
  r[4] = (bf16)b.x; r[5] = (bf16)b.y; r[6] = (bf16)b.z; r[7] = (bf16)b.w;
  return r;
}

// ---------- f32 -> bf16 bulk convert (contiguous) ----------
__global__ void k_cvt(const float* __restrict__ s, bf16* __restrict__ d, long n) {
  long stride = (long)gridDim.x * blockDim.x;
  for (long i = (long)blockIdx.x * blockDim.x + threadIdx.x; i * 8 < n; i += stride) {
    long e = i * 8;
    if (e + 8 <= n) {
      float4 a = *(const float4*)(s + e);
      float4 b = *(const float4*)(s + e + 4);
      *(bf16x8*)(d + e) = pack8(a, b);
    } else {
      for (long j = e; j < n; j++) d[j] = (bf16)s[j];
    }
  }
}

// ---------- build xbE: row m = [cvt(x[m,:H]) | feats[m,:DC] | zeros] (ld = KE) ----------
__global__ void k_xext(const float* __restrict__ x, const float* __restrict__ feats,
                       bf16* __restrict__ xbE, int H, int KE, int DC, long BT) {
  int wave = threadIdx.x >> 6, lane = threadIdx.x & 63;
  long m = (long)blockIdx.x * 4 + wave;
  if (m >= BT) return;
  const float* xp = x + m * H;
  bf16* dp = xbE + m * KE;
  for (int e = lane * 8; e + 8 <= H; e += 512) {
    float4 a = *(const float4*)(xp + e);
    float4 b = *(const float4*)(xp + e + 4);
    *(bf16x8*)(dp + e) = pack8(a, b);
  }
  int pad = KE - H;
  if (lane < pad)
    dp[H + lane] = (lane < DC) ? (bf16)feats[m * DC + lane] : (bf16)0.f;
}

// ---------- build W1bE: row n = [cvt(W1[n,:H]) | cvt(W1[n,H:H+DC]) | zeros] ----------
__global__ void k_w1ext(const float* __restrict__ W1, bf16* __restrict__ W1bE,
                        int H, int DIN, int KE, int DC, long N2) {
  int wave = threadIdx.x >> 6, lane = threadIdx.x & 63;
  long n = (long)blockIdx.x * 4 + wave;
  if (n >= N2) return;
  const float* sp = W1 + n * DIN;
  bf16* dp = W1bE + n * KE;
  for (int e = lane * 8; e + 8 <= H; e += 512) {
    float4 a = *(const float4*)(sp + e);
    float4 b = *(const float4*)(sp + e + 4);
    *(bf16x8*)(dp + e) = pack8(a, b);
  }
  int pad = KE - H;
  if (lane < pad)
    dp[H + lane] = (lane < DC) ? (bf16)sp[H + lane] : (bf16)0.f;
}

// ---------- seed out_y with wb2 (broadcast over T) ----------
__global__ void k_init(float* __restrict__ outY, const float* __restrict__ wb2,
                       int H, int T, long BT) {
  int wave = threadIdx.x >> 6, lane = threadIdx.x & 63;
  long gm = (long)blockIdx.x * 4 + wave;
  if (gm >= BT) return;
  int b = (int)(gm / T);
  const float* s = wb2 + (size_t)b * H;
  float* d = outY + gm * H;
  for (int e = lane * 4; e + 4 <= H; e += 256)
    *(float4*)(d + e) = *(const float4*)(s + e);
}

// ---------- concept feats: compile-time DC hot loop (register-resident) ----------
template <int DCT>
__global__ void k_feats_t(const float* __restrict__ x,
                          const float* __restrict__ Wtt, const float* __restrict__ btt,
                          const float* __restrict__ Wpol, const float* __restrict__ bpol,
                          float* __restrict__ out_tt, float* __restrict__ out_pol,
                          float* __restrict__ feats, float* __restrict__ fsum,
                          int H, int T, int BT, int C1, int C2) {
  int wave = threadIdx.x >> 6, lane = threadIdx.x & 63;
  int site = blockIdx.x * 4 + wave;
  if (site >= BT) return;
  int b = site / T;
  const float* xp = x + (size_t)site * H;
  const float* wp[DCT];
#pragma unroll
  for (int c = 0; c < DCT; c++)
    wp[c] = (c < C1) ? (Wtt + (size_t)c * H) : (Wpol + (size_t)(c - C1) * H);
  float acc[DCT];
#pragma unroll
  for (int c = 0; c < DCT; c++) acc[c] = 0.f;
  for (int k = lane * 4; k < H; k += 256) {
    float4 xv = *(const float4*)(xp + k);
#pragma unroll
    for (int c = 0; c < DCT; c++) {
      float4 wv4 = *(const float4*)(wp[c] + k);
      acc[c] += xv.x * wv4.x + xv.y * wv4.y + xv.z * wv4.z + xv.w * wv4.w;
    }
  }
#pragma unroll
  for (int c = 0; c < DCT; c++) acc[c] = wsum(acc[c]);
  if (lane == 0) {
#pragma unroll
    for (int c = 0; c < DCT; c++) {
      float val = acc[c] + (c < C1 ? btt[c] : bpol[c - C1]);
      if (c < C1) out_tt[(size_t)site * C1 + c] = val;
      else        out_pol[(size_t)site * C2 + (c - C1)] = val;
      feats[(size_t)site * DCT + c] = val;
      atomicAdd(&fsum[b * DCT + c], val / (float)T);
    }
  }
}

// generic fallback (runtime DC) — correctness path only
__global__ void k_feats_g(const float* __restrict__ x,
                          const float* __restrict__ Wtt, const float* __restrict__ btt,
                          const float* __restrict__ Wpol, const float* __restrict__ bpol,
                          float* __restrict__ out_tt, float* __restrict__ out_pol,
                          float* __restrict__ feats, float* __restrict__ fsum,
                          int H, int T, int BT, int C1, int C2) {
  int wave = threadIdx.x >> 6, lane = threadIdx.x & 63;
  int site = blockIdx.x * 4 + wave;
  if (site >= BT) return;
  int DC = C1 + C2;
  int b = site / T;
  const float* xp = x + (size_t)site * H;
  for (int c = 0; c < DC; c++) {
    const float* wr = (c < C1) ? (Wtt + (size_t)c * H) : (Wpol + (size_t)(c - C1) * H);
    float a = 0.f;
    for (int k = lane; k < H; k += 64) a += xp[k] * wr[k];
    a = wsum(a);
    if (lane == 0) {
      float val = a + (c < C1 ? btt[c] : bpol[c - C1]);
      if (c < C1) out_tt[(size_t)site * C1 + c] = val;
      else        out_pol[(size_t)site * C2 + (c - C1)] = val;
      feats[(size_t)site * DC + c] = val;
      atomicAdd(&fsum[b * DC + c], val / (float)T);
    }
  }
}

// ---------- pooled mean over T ----------
__global__ void k_pool(const float* __restrict__ x, float* __restrict__ pooled,
                       int H, int T, int tsplit) {
  int hBlocks = (H + 255) / 256;
  int bs = blockIdx.x / tsplit, ts = blockIdx.x % tsplit;
  int b = bs / hBlocks;
  int h = (bs % hBlocks) * 256 + threadIdx.x;
  if (h >= H) return;
  int tlo = (int)(((long)T * ts) / tsplit), thi = (int)(((long)T * (ts + 1)) / tsplit);
  const float* p = x + (size_t)b * T * H + h;
  float s = 0.f;
  for (int t = tlo; t < thi; t++) s += p[(size_t)t * H];
  atomicAdd(&pooled[(size_t)b * H + h], s / (float)T);
}

// ---------- context -> h0 ----------
__global__ void k_ctx_h0(const float* __restrict__ Wc2h, const float* __restrict__ bc2h,
                         const float* __restrict__ pooled, const float* __restrict__ fmean,
                         float* __restrict__ h0, float* __restrict__ out_pool,
                         int H, int DIN, int B, int DC) {
  int wave = threadIdx.x >> 6, lane = threadIdx.x & 63;
  int r = blockIdx.x * 4 + wave;
  if (r >= B * H) return;
  int b = r / H, j = r % H;
  const float* wrow = Wc2h + (size_t)j * DIN;
  float a = 0.f;
  for (int k = lane; k < DIN; k += 64) {
    float cv = (k < H) ? pooled[(size_t)b * H + k] : fmean[b * DC + (k - H)];
    a += cv * wrow[k];
  }
  a = wsum(a);
  if (lane == 0) {
    h0[r] = a + bc2h[j];
    out_pool[r] = pooled[r];
  }
}

// ---------- one GRU step ----------
__global__ void k_gru(const float* __restrict__ hin, const float* __restrict__ Whh,
                      const float* __restrict__ bih, const float* __restrict__ bhh,
                      float* __restrict__ hout, float* __restrict__ hsl,
                      int H, int B) {
  int wave = threadIdx.x >> 6, lane = threadIdx.x & 63;
  int r = blockIdx.x * 4 + wave;
  if (r >= B * H) return;
  int b = r / H, j = r % H;
  const float* h = hin + (size_t)b * H;
  const float* w0 = Whh + (size_t)j * H;
  const float* w1 = Whh + (size_t)(H + j) * H;
  const float* w2 = Whh + (size_t)(2 * H + j) * H;
  float ar = 0, az = 0, an = 0;
  for (int k = lane; k < H; k += 64) {
    float hv = h[k];
    ar += hv * w0[k];
    az += hv * w1[k];
    an += hv * w2[k];
  }
  ar = wsum(ar); az = wsum(az); an = wsum(an);
  if (lane == 0) {
    float ghr = ar + bhh[j];
    float ghz = az + bhh[H + j];
    float ghn = an + bhh[2 * H + j];
    float rg = 1.f / (1.f + expf(-(bih[j] + ghr)));
    float zg = 1.f / (1.f + expf(-(bih[H + j] + ghz)));
    float ng = tanhf(bih[2 * H + j] + rg * ghn);
    float hn = (1.f - zg) * ng + zg * h[j];
    hout[r] = hn;
    hsl[r] = hn;
  }
}

// ---------- program logits ----------
__global__ void k_logits(const float* __restrict__ hs, const float* __restrict__ Wproj,
                         const float* __restrict__ bproj, float* __restrict__ logits,
                         float* __restrict__ out_log, int H, int B, int L, int V) {
  int wave = threadIdx.x >> 6, lane = threadIdx.x & 63;
  int r = blockIdx.x * 4 + wave;
  if (r >= B * L * V) return;
  int b = r / (L * V), rem = r % (L * V), l = rem / V, u = rem % V;
  const float* h = hs + ((size_t)l * B + b) * H;
  const float* w = Wproj + (size_t)u * H;
  float a = 0.f;
  for (int k = lane; k < H; k += 64) a += h[k] * w[k];
  a = wsum(a);
  if (lane == 0) {
    a += bproj[u];
    int idx = (b * L + l) * V + u;
    logits[idx] = a;
    out_log[idx] = a;
  }
}

// ---------- w[b,v] = mean_l softmax(logits);  wb2[b,o] = sum_v w*b2 ----------
__global__ void k_wmix(const float* __restrict__ logits, const float* __restrict__ b2,
                       float* __restrict__ wv, float* __restrict__ wb2,
                       int B, int L, int V, int H) {
  __shared__ float sm[2048];
  __shared__ float wsh[512];
  int t = threadIdx.x;
  if (t < B * L) {
    const float* lg = logits + t * V;
    float mx = lg[0];
    for (int u = 1; u < V; u++) mx = fmaxf(mx, lg[u]);
    float s = 0.f;
    for (int u = 0; u < V; u++) s += expf(lg[u] - mx);
    for (int u = 0; u < V; u++) sm[t * V + u] = expf(lg[u] - mx) / s;
  }
  __syncthreads();
  if (t < B * V) {
    int b = t / V, u = t % V;
    float a = 0.f;
    for (int l = 0; l < L; l++) a += sm[(b * L + l) * V + u];
    a /= (float)L;
    wsh[t] = a;
    wv[t] = a;
  }
  __syncthreads();
  for (int idx = t; idx < B * H; idx += 256) {
    int b = idx / H, o = idx % H;
    float a = 0.f;
    for (int u = 0; u < V; u++) a += wsh[b * V + u] * b2[(size_t)u * H + o];
    wb2[idx] = a;
  }
}

// ---------- MFMA GEMM1: hmid = wv * gelu(xbE·W1bE^T + b1)  (tail folded into K) ----------
__global__ __launch_bounds__(256, 2) void gemm1_mfma(
    const bf16* __restrict__ A, const bf16* __restrict__ Bb, bf16* __restrict__ hmid,
    const float* __restrict__ b1, const float* __restrict__ wv,
    int rows, long moff, int KE, int H, int N, int T, int V) {
  __shared__ __align__(16) bf16 As[128 * 32];
  __shared__ __align__(16) bf16 Bs[128 * 32];
  const int wave = threadIdx.x >> 6, lane = threadIdx.x & 63;
  const int m0 = blockIdx.y * 128, n0 = blockIdx.x * 128;
  const int mw = (wave >> 1) * 64, nw = (wave & 1) * 64;
  const int sRow = lane >> 2, sK = (lane & 3) * 8;
  const int rA = lane & 15, q8 = (lane >> 4) * 8;
  f32x4 acc[4][4];
#pragma unroll
  for (int i = 0; i < 4; i++)
#pragma unroll
    for (int j = 0; j < 4; j++) acc[i][j] = (f32x4){0.f, 0.f, 0.f, 0.f};

  int arow[2], brow[2];
#pragma unroll
  for (int t = 0; t < 2; ++t) {
    int s = wave * 2 + t;
    int r = s * 16 + sRow;
    arow[t] = (m0 + r < rows) ? (m0 + r) : (rows - 1);
    brow[t] = (n0 + r < N) ? (n0 + r) : (N - 1);
  }

  for (int k0 = 0; k0 < KE; k0 += 32) {
    __syncthreads();
#pragma unroll
    for (int t = 0; t < 2; ++t) {
      int s = wave * 2 + t;
      g2l16(A + (size_t)arow[t] * KE + k0 + sK, &As[s * 512]);
      g2l16(Bb + (size_t)brow[t] * KE + k0 + sK, &Bs[s * 512]);
    }
    __syncthreads();
    bf16x8 af[4], bf_[4];
#pragma unroll
    for (int i = 0; i < 4; i++) af[i] = *(const bf16x8*)&As[(mw + i * 16 + rA) * 32 + q8];
#pragma unroll
    for (int j = 0; j < 4; j++) bf_[j] = *(const bf16x8*)&Bs[(nw + j * 16 + rA) * 32 + q8];
#pragma unroll
    for (int i = 0; i < 4; i++)
#pragma unroll
      for (int j = 0; j < 4; j++)
        acc[i][j] = __builtin_amdgcn_mfma_f32_16x16x32_bf16(af[i], bf_[j], acc[i][j], 0, 0, 0);
  }

  int vj[4];
  float b1j[4];
#pragma unroll
  for (int j = 0; j < 4; j++) {
    int n = n0 + nw + j * 16 + rA;
    if (n >= N) n = N - 1;
    vj[j] = n / H;
    b1j[j] = b1[n];
  }
#pragma unroll
  for (int i = 0; i < 4; i++) {
#pragma unroll
    for (int r = 0; r < 4; r++) {
      int m = m0 + mw + i * 16 + (lane >> 4) * 4 + r;
      if (m >= rows) continue;
      long gm = moff + m;
      int b = (int)(gm / T);
#pragma unroll
      for (int j = 0; j < 4; j++) {
        int n = n0 + nw + j * 16 + rA;
        if (n >= N) continue;
        float val = acc[i][j][r] + b1j[j];
        val = 0.5f * val * (1.0f + erff(val * 0.70710678118654752f));
        val *= wv[b * V + vj[j]];
        hmid[(size_t)m * N + n] = (bf16)val;
      }
    }
  }
}

// ---------- MFMA GEMM2 (K-split x ZS, atomic accumulate): out += hmid·W2b^T ----------
__global__ __launch_bounds__(256, 2) void gemm2_mfma(
    const bf16* __restrict__ A, const bf16* __restrict__ W2b, float* __restrict__ outY,
    int rows, long moff, int H, int K, int T, int kchunk) {
  __shared__ __align__(16) bf16 As[128 * 32];
  __shared__ __align__(16) bf16 Bs[128 * 32];
  const int wave = threadIdx.x >> 6, lane = threadIdx.x & 63;
  const int m0 = blockIdx.y * 128, n0 = blockIdx.x * 128;
  const int mw = (wave >> 1) * 64, nw = (wave & 1) * 64;
  const int sRow = lane >> 2, sK = (lane & 3) * 8;
  const int rA = lane & 15, q8 = (lane >> 4) * 8;
  int kz0 = blockIdx.z * kchunk;
  int kz1 = kz0 + kchunk; if (kz1 > K) kz1 = K;
  if (kz0 >= K) return;
  f32x4 acc[4][4];
#pragma unroll
  for (int i = 0; i < 4; i++)
#pragma unroll
    for (int j = 0; j < 4; j++) acc[i][j] = (f32x4){0.f, 0.f, 0.f, 0.f};

  int arow[2], brow[2];
#pragma unroll
  for (int t = 0; t < 2; ++t) {
    int s = wave * 2 + t;
    int r = s * 16 + sRow;
    arow[t] = (m0 + r < rows) ? (m0 + r) : (rows - 1);
    brow[t] = (n0 + r < H) ? (n0 + r) : (H - 1);
  }

  int kv = kz0 / H, kh = kz0 % H;
  for (int k0 = kz0; k0 < kz1; k0 += 32) {
    const bf16* Bk = W2b + (size_t)kv * H * H + kh;
    __syncthreads();
#pragma unroll
    for (int t = 0; t < 2; ++t) {
      int s = wave * 2 + t;
      g2l16(A + (size_t)arow[t] * K + k0 + sK, &As[s * 512]);
      g2l16(Bk + (size_t)brow[t] * H + sK, &Bs[s * 512]);
    }
    __syncthreads();
    bf16x8 af[4], bf_[4];
#pragma unroll
    for (int i = 0; i < 4; i++) af[i] = *(const bf16x8*)&As[(mw + i * 16 + rA) * 32 + q8];
#pragma unroll
    for (int j = 0; j < 4; j++) bf_[j] = *(const bf16x8*)&Bs[(nw + j * 16 + rA) * 32 + q8];
#pragma unroll
    for (int i = 0; i < 4; i++)
#pragma unroll
      for (int j = 0; j < 4; j++)
        acc[i][j] = __builtin_amdgcn_mfma_f32_16x16x32_bf16(af[i], bf_[j], acc[i][j], 0, 0, 0);
    kh += 32;
    if (kh >= H) { kh = 0; kv++; }
  }

#pragma unroll
  for (int i = 0; i < 4; i++) {
#pragma unroll
    for (int r = 0; r < 4; r++) {
      int m = m0 + mw + i * 16 + (lane >> 4) * 4 + r;
      if (m >= rows) continue;
      long gm = moff + m;
#pragma unroll
      for (int j = 0; j < 4; j++) {
        int n = n0 + nw + j * 16 + rA;
        if (n >= H) continue;
        atomicAdd(&outY[(size_t)gm * H + n], acc[i][j][r]);
      }
    }
  }
}

extern "C" void kernel_launch(void* const* d_in, const int* in_sizes, int n_in,
                              void* d_out, int out_size, void* d_ws, size_t ws_size,
                              hipStream_t stream) {
  const float* x      = (const float*)d_in[0];
  const float* W_tt   = (const float*)d_in[1];
  const float* b_tt   = (const float*)d_in[2];
  const float* W_pol  = (const float*)d_in[3];
  const float* b_pol  = (const float*)d_in[4];
  const float* W_c2h  = (const float*)d_in[5];
  const float* b_c2h  = (const float*)d_in[6];
  const float* W_hh   = (const float*)d_in[8];
  const float* b_ih   = (const float*)d_in[9];
  const float* b_hh   = (const float*)d_in[10];
  const float* W_proj = (const float*)d_in[11];
  const float* b_proj = (const float*)d_in[12];
  const float* W1     = (const float*)d_in[13];
  const float* b1     = (const float*)d_in[14];
  const float* W2     = (const float*)d_in[15];
  const float* b2     = (const float*)d_in[16];
  float* out = (float*)d_out;
  char* ws = (char*)d_ws;

  const int C1 = in_sizes[2];
  const int C2 = in_sizes[4];
  const int H  = in_sizes[1] / C1;
  const int DC = C1 + C2;
  const int DIN = H + DC;
  const int V  = in_sizes[12];
  const long BT = (long)in_sizes[0] / H;
  long R = (long)out_size - BT * (long)(H + DC);
  int B = 0, L = 0;
  for (int Lc = 1; Lc <= 32; ++Lc) {
    long den = (long)Lc * V + H;
    if (R % den == 0) {
      long Bc = R / den;
      if (Bc >= 1 && BT % Bc == 0) {
        if (B == 0 || Lc == 4) { B = (int)Bc; L = Lc; }
        if (Lc == 4) break;
      }
    }
  }
  if (B == 0) { B = 8; L = 4; }
  const int T = (int)(BT / B);
  const long N2 = (long)V * H;
  const int KE = H + 32;

  size_t o = 0;
  auto alloc = [&](size_t bytes) { size_t r = o; o = (o + bytes + 255) & ~(size_t)255; return r; };
  float* feats  = (float*)(ws + alloc((size_t)BT * DC * 4));
  size_t off_pooled = alloc((size_t)B * H * 4);
  float* pooled = (float*)(ws + off_pooled);
  size_t off_fsum = alloc((size_t)B * DC * 4);
  float* fsum   = (float*)(ws + off_fsum);
  float* hbuf   = (float*)(ws + alloc((size_t)2 * B * H * 4));
  float* hs     = (float*)(ws + alloc((size_t)L * B * H * 4));
  float* logits = (float*)(ws + alloc((size_t)B * L * V * 4));
  float* wv     = (float*)(ws + alloc((size_t)B * V * 4));
  float* wb2    = (float*)(ws + alloc((size_t)B * H * 4));
  bf16* xbE  = (bf16*)(ws + alloc((size_t)BT * KE * 2));
  bf16* W1bE = (bf16*)(ws + alloc((size_t)N2 * KE * 2));
  bf16* W2b  = (bf16*)(ws + alloc((size_t)N2 * H * 2));
  size_t off_hmid = alloc(0);
  long avail = (long)ws_size - (long)off_hmid;
  long mcMax = avail / (N2 * 2);
  long Mc = (mcMax / 128) * 128;
  long bt128 = ((BT + 127) / 128) * 128;
  if (Mc > bt128) Mc = bt128;
  if (Mc < 128) Mc = 128;
  bf16* hmid = (bf16*)(ws + off_hmid);

  float* out_y    = out;
  float* out_log  = out_y + (size_t)BT * H;
  float* out_tt   = out_log + (size_t)B * L * V;
  float* out_pol  = out_tt + (size_t)BT * C1;
  float* out_pool = out_pol + (size_t)BT * C2;

  hipMemsetAsync(ws + off_pooled, 0, off_fsum - off_pooled + (size_t)B * DC * 4, stream);

  k_cvt<<<4096, 256, 0, stream>>>(W2, W2b, N2 * (long)H);
  if (DC == 8 && (H & 1023) == 0)
    k_feats_t<8><<<(int)((BT + 3) / 4), 256, 0, stream>>>(x, W_tt, b_tt, W_pol, b_pol,
                                                          out_tt, out_pol, feats, fsum,
                                                          H, T, (int)BT, C1, C2);
  else
    k_feats_g<<<(int)((BT + 3) / 4), 256, 0, stream>>>(x, W_tt, b_tt, W_pol, b_pol,
                                                       out_tt, out_pol, feats, fsum,
                                                       H, T, (int)BT, C1, C2);
  k_xext<<<(int)((BT + 3) / 4), 256, 0, stream>>>(x, feats, xbE, H, KE, DC, BT);
  k_w1ext<<<(int)((N2 + 3) / 4), 256, 0, stream>>>(W1, W1bE, H, DIN, KE, DC, N2);
  int hBlocks = (H + 255) / 256;
  k_pool<<<B * hBlocks * 8, 256, 0, stream>>>(x, pooled, H, T, 8);
  k_ctx_h0<<<(B * H + 3) / 4, 256, 0, stream>>>(W_c2h, b_c2h, pooled, fsum,
                                                hbuf, out_pool, H, DIN, B, DC);
  float* hA = hbuf;
  float* hB = hbuf + (size_t)B * H;
  for (int l = 0; l < L; ++l) {
    k_gru<<<(B * H + 3) / 4, 256, 0, stream>>>((l & 1) ? hB : hA, W_hh, b_ih, b_hh,
                                               (l & 1) ? hA : hB, hs + (size_t)l * B * H,
                                               H, B);
  }
  k_logits<<<(B * L * V + 3) / 4, 256, 0, stream>>>(hs, W_proj, b_proj, logits,
                                                    out_log, H, B, L, V);
  k_wmix<<<1, 256, 0, stream>>>(logits, b2, wv, wb2, B, L, V, H);
  k_init<<<(int)((BT + 3) / 4), 256, 0, stream>>>(out_y, wb2, H, T, BT);

  const int ZS = 4;
  int kchunk = (int)((((N2 / ZS) + 31) / 32) * 32);
  for (long moff = 0; moff < BT; moff += Mc) {
    int rows = (int)(((BT - moff) < Mc) ? (BT - moff) : Mc);
    dim3 g1((unsigned)((N2 + 127) / 128), (unsigned)((rows + 127) / 128));
    dim3 g2((unsigned)((H + 127) / 128), (unsigned)((rows + 127) / 128), ZS);
    gemm1_mfma<<<g1, 256, 0, stream>>>(xbE + (size_t)moff * KE, W1bE, hmid, b1, wv,
                                       rows, moff, KE, H, (int)N2, T, V);
    gemm2_mfma<<<g2, 256, 0, stream>>>(hmid, W2b, out_y,
                                       rows, moff, H, (int)N2, T, kchunk);
  }
}